// Round 5
// baseline (208.546 us; speedup 1.0000x reference)
//
#include <hip/hip_runtime.h>
#include <math.h>
#include <stdint.h>

// Problem constants
#define B_ 2
#define L_ 2048
#define D_ 1024
#define H_ 16
#define HD_ 64
// Q scale = 1/8 (softmax scale) * log2(e), folding exp->exp2
#define QSCALE_ 0.1803368801f

typedef __attribute__((ext_vector_type(8))) short short8;   // 8 bf16 = 4 VGPRs (MFMA A/B frag)
typedef __attribute__((ext_vector_type(4))) short short4v;
typedef __attribute__((ext_vector_type(4))) float float4v;  // MFMA C/D frag

#if defined(__has_builtin)
#if __has_builtin(__builtin_amdgcn_exp2f)
#define EXP2F(x) __builtin_amdgcn_exp2f(x)
#endif
#endif
#ifndef EXP2F
#define EXP2F(x) exp2f(x)
#endif

// fp32 -> bf16 round-to-nearest-even (bit pattern as short)
__device__ __forceinline__ short f2bf(float f) {
    union { float f; unsigned u; } x; x.f = f;
    unsigned r = x.u + 0x7fffu + ((x.u >> 16) & 1u);
    return (short)(r >> 16);
}

__device__ __forceinline__ unsigned fbits(float f) {
    union { float f; unsigned u; } x; x.f = f;
    return x.u;
}

// pack trunc-bf16(a) | trunc-bf16(b)<<16 in ONE v_perm_b32:
// bytes {b.b3, b.b2, a.b3, a.b2}; sel indexes concat[S0=bytes4-7 | S1=bytes0-3]
__device__ __forceinline__ unsigned pk_bf_trunc(float a, float b) {
    return __builtin_amdgcn_perm(fbits(b), fbits(a), 0x07060302u);
}

// async global->LDS, 16B per lane. dst must be wave-uniform; HW writes dst + lane*16.
__device__ __forceinline__ void gl_lds16(const void* g, void* l) {
    __builtin_amdgcn_global_load_lds(
        (const __attribute__((address_space(1))) unsigned int*)g,
        (__attribute__((address_space(3))) unsigned int*)l, 16, 0, 0);
}

// ---------------------------------------------------------------------------
// Weight cast: w_qkv (786432 float4 groups) + w_proj (262144 groups), 1 launch
// ---------------------------------------------------------------------------
__global__ __launch_bounds__(256) void cvt_w(const float* __restrict__ wqkv,
                                             const float* __restrict__ wproj,
                                             short* __restrict__ wqkvb,
                                             short* __restrict__ wprojb) {
    int i = blockIdx.x * 256 + threadIdx.x;   // grid 4096*256 = 1048576 groups exactly
    const float* in;
    short* out;
    int idx;
    if (i < 786432) { in = wqkv;  out = wqkvb;  idx = i; }
    else            { in = wproj; out = wprojb; idx = i - 786432; }
    float4 v = ((const float4*)in)[idx];
    short4v o;
    o.x = f2bf(v.x); o.y = f2bf(v.y); o.z = f2bf(v.z); o.w = f2bf(v.w);
    ((short4v*)out)[idx] = o;
}

// ---------------------------------------------------------------------------
// QKV GEMM (bf16 MFMA): C[m,n] = sum_k X[m,k]*W[n,k]
// X read as FP32 directly (cast fused into A-staging, prefetch distance 1);
// W read bf16 via gl_lds16. 128x128 tile, BK=32, 4 waves 2x2, 4x4 16x16 tiles.
// Q scattered [b,h,l,d] scaled by 0.125*log2e; K [b,h,l,d]; V^T [b,h,d,kpos].
// Q/K epilogue bounces tile through LDS -> coalesced 16B stores.
// ---------------------------------------------------------------------------
__global__ __launch_bounds__(256) void gemm_qkv_bf16(const float* __restrict__ X,
                                                     const short* __restrict__ Bm,
                                                     short* __restrict__ Qb,
                                                     short* __restrict__ Kb,
                                                     short* __restrict__ Vb) {
    __shared__ short smem[8192];          // As = smem[0:4096], Bs = smem[4096:8192]
    short* As = smem;
    short* Bs = smem + 4096;
    const int tid = threadIdx.x;
    const int w = tid >> 6, l = tid & 63;
    const int lm = l & 15, q = l >> 4;
    const int m0 = blockIdx.y * 128, n0 = blockIdx.x * 128;
    const int wm = w >> 1, wn = w & 1;

    // A-staging geometry: chunk c = tid + 256*j -> row = c>>3 (0..127), col4 = c&7
    int arow_[4], acol_[4];
#pragma unroll
    for (int j = 0; j < 4; ++j) {
        int c = tid + 256 * j;
        arow_[j] = c >> 3;
        acol_[j] = (c & 7) * 4;
    }

    float4v acc[4][4];
#pragma unroll
    for (int mt = 0; mt < 4; ++mt)
#pragma unroll
        for (int nt = 0; nt < 4; ++nt) acc[mt][nt] = (float4v){0.f, 0.f, 0.f, 0.f};

    // preload A k-tile 0 (fp32)
    float4 areg[4];
#pragma unroll
    for (int j = 0; j < 4; ++j)
        areg[j] = *(const float4*)(X + (size_t)(m0 + arow_[j]) * 1024 + acol_[j]);

    for (int k0 = 0; k0 < 1024; k0 += 32) {
        __syncthreads();
        // stage A (convert fp32->bf16 RTE), 16 elems/thread
#pragma unroll
        for (int j = 0; j < 4; ++j) {
            short4v s4;
            s4.x = f2bf(areg[j].x); s4.y = f2bf(areg[j].y);
            s4.z = f2bf(areg[j].z); s4.w = f2bf(areg[j].w);
            *(short4v*)(As + arow_[j] * 32 + acol_[j]) = s4;
        }
        // stage B via async global->LDS
#pragma unroll
        for (int t = 0; t < 2; ++t) {
            int idx8 = w * 128 + t * 64 + l;
            int row = idx8 >> 2, c8 = idx8 & 3;
            gl_lds16(Bm + (size_t)(n0 + row) * 1024 + k0 + c8 * 8, (char*)Bs + w * 2048 + t * 1024);
        }
        __syncthreads();
        // prefetch next A k-tile (in flight during compute)
        if (k0 < 992) {
#pragma unroll
            for (int j = 0; j < 4; ++j)
                areg[j] = *(const float4*)(X + (size_t)(m0 + arow_[j]) * 1024 + k0 + 32 + acol_[j]);
        }
        short8 af[4], bfr[4];
#pragma unroll
        for (int mt = 0; mt < 4; ++mt)
            af[mt] = *(const short8*)(As + (wm * 64 + mt * 16 + lm) * 32 + q * 8);
#pragma unroll
        for (int nt = 0; nt < 4; ++nt)
            bfr[nt] = *(const short8*)(Bs + (wn * 64 + nt * 16 + lm) * 32 + q * 8);
#pragma unroll
        for (int mt = 0; mt < 4; ++mt)
#pragma unroll
            for (int nt = 0; nt < 4; ++nt)
                acc[mt][nt] = __builtin_amdgcn_mfma_f32_16x16x32_bf16(af[mt], bfr[nt], acc[mt][nt], 0, 0, 0);
    }

    // C layout: col = lane&15, row = quad*4 + reg
    const int which = n0 >> 10;   // uniform per block: 0=Q, 1=K, 2=V
    if (which < 2) {
        short* dst = (which == 0) ? Qb : Kb;
        const float sc = (which == 0) ? QSCALE_ : 1.0f;
        // bounce through LDS in two 64-row halves for coalesced 16B stores
#pragma unroll
        for (int half = 0; half < 2; ++half) {
            __syncthreads();
            if (wm == half) {
#pragma unroll
                for (int mt = 0; mt < 4; ++mt)
#pragma unroll
                    for (int nt = 0; nt < 4; ++nt)
#pragma unroll
                        for (int r = 0; r < 4; ++r)
                            smem[(mt * 16 + q * 4 + r) * 128 + wn * 64 + nt * 16 + lm] =
                                f2bf(acc[mt][nt][r] * sc);
            }
            __syncthreads();
#pragma unroll
            for (int j = 0; j < 4; ++j) {
                const int x = tid + 256 * j;
                const int row = x >> 4, c = x & 15;
                short8 v = *(const short8*)(smem + row * 128 + c * 8);
                const int m = m0 + half * 64 + row;
                const int b = m >> 11, ll = m & 2047;
                const int n = n0 + c * 8;
                const int hh = (n & 1023) >> 6, d = n & 63;
                *(short8*)(dst + (((size_t)b * H_ + hh) * L_ + ll) * HD_ + d) = v;
            }
        }
    } else {
        // V^T: [b][h][d][kpos]; r indexes 4 consecutive kpos -> packed 8B store
#pragma unroll
        for (int mt = 0; mt < 4; ++mt) {
            const int m = m0 + wm * 64 + mt * 16 + q * 4;   // kpos base
            const int b = m >> 11, ll = m & 2047;
#pragma unroll
            for (int nt = 0; nt < 4; ++nt) {
                const int n = n0 + wn * 64 + nt * 16 + lm;
                const int h = (n & 1023) >> 6, d = n & 63;
                short4v pk;
                pk.x = f2bf(acc[mt][nt][0]); pk.y = f2bf(acc[mt][nt][1]);
                pk.z = f2bf(acc[mt][nt][2]); pk.w = f2bf(acc[mt][nt][3]);
                *(short4v*)(Vb + (((size_t)b * H_ + h) * HD_ + d) * L_ + ll) = pk;
            }
        }
    }
}

// ---------------------------------------------------------------------------
// Flash attention v4: block = 128 q-rows x (b,h); 4 waves, wave owns 32 rows.
// S^T = K Q^T, exp2 (scale folded into Q), P packed via v_perm trunc-bf16
// (1 op / 2 elems), PV as O^T = V^T P^T. K/V double-buffered, 1 barrier/iter.
// Q staged through the Pt buffer (dead after qf regs read) -> LDS 50 KB.
// ---------------------------------------------------------------------------
__global__ __launch_bounds__(256) void attn_mfma(const short* __restrict__ Qb,
                                                 const short* __restrict__ Kb,
                                                 const short* __restrict__ Vtg,
                                                 short* __restrict__ Ob) {
    __shared__ short KV[4 * 4096];   // buf0: K,V ; buf1: K,V (each 64x64 swizzled)
    __shared__ short Pt[128 * 72];   // [qrow][kpos] stride 72; also Q staging area

    const int tid = threadIdx.x;
    const int w = tid >> 6, l = tid & 63;
    const int lm = l & 15, q = l >> 4;
    const int qt = blockIdx.x, bh = blockIdx.y;

    const short* Qg = Qb  + ((size_t)bh * L_ + qt * 128) * HD_;
    const short* Kg = Kb  + (size_t)bh * L_ * HD_;
    const short* Vg = Vtg + (size_t)bh * HD_ * L_;

    // ---- stage Q once into Pt (swizzled, stride 64); consumed into regs below ----
#pragma unroll
    for (int t = 0; t < 4; ++t) {
        int idx = tid + 256 * t;
        int row = idx >> 3, c = idx & 7;
        short8 v = *(const short8*)(Qg + row * 64 + c * 8);
        *(short8*)(Pt + row * 64 + ((c ^ (row & 7)) * 8)) = v;
    }

    // K/V staging geometry
    const int srow = tid >> 3;            // 0..31
    const int sc   = tid & 7;             // 0..7
    const int koff0 = srow * 64 + ((sc ^ (srow & 7)) * 8);
    const int koff1 = koff0 + 32 * 64;    // (srow+32)&7 == srow&7

    // tile 0 -> buf0 now; tile 1 -> regs
    {
        short8 ka = *(const short8*)(Kg + (size_t)srow * 64 + sc * 8);
        short8 kb = *(const short8*)(Kg + (size_t)(srow + 32) * 64 + sc * 8);
        short8 va = *(const short8*)(Vg + (size_t)srow * L_ + sc * 8);
        short8 vb = *(const short8*)(Vg + (size_t)(srow + 32) * L_ + sc * 8);
        *(short8*)(KV + koff0) = ka;
        *(short8*)(KV + koff1) = kb;
        *(short8*)(KV + 4096 + koff0) = va;
        *(short8*)(KV + 4096 + koff1) = vb;
    }
    short8 kra = *(const short8*)(Kg + (size_t)(64 + srow) * 64 + sc * 8);
    short8 krb = *(const short8*)(Kg + (size_t)(64 + srow + 32) * 64 + sc * 8);
    short8 vra = *(const short8*)(Vg + (size_t)srow * L_ + 64 + sc * 8);
    short8 vrb = *(const short8*)(Vg + (size_t)(srow + 32) * L_ + 64 + sc * 8);

    __syncthreads();   // Q + buf0 staged

    // Q fragments (loop-invariant, own 32 rows) -- read from Pt, then Pt is dead
    short8 qf[2][2];
#pragma unroll
    for (int nq = 0; nq < 2; ++nq)
#pragma unroll
        for (int kh = 0; kh < 2; ++kh) {
            int row = w * 32 + nq * 16 + lm;
            int ch = kh * 4 + q;
            qf[nq][kh] = *(const short8*)(Pt + row * 64 + ((ch ^ (row & 7)) * 8));
        }

    // hoisted frag offsets (iter-invariant)
    int offA0[4], offA1[4], offV[2][4];
#pragma unroll
    for (int nt = 0; nt < 4; ++nt) {
        const int arow = nt * 16 + lm;
        offA0[nt] = arow * 64 + ((q ^ (arow & 7)) * 8);
        offA1[nt] = arow * 64 + (((4 + q) ^ (arow & 7)) * 8);
#pragma unroll
        for (int kh = 0; kh < 2; ++kh)
            offV[kh][nt] = arow * 64 + (((kh * 4 + q) ^ (arow & 7)) * 8);
    }

    float4v o[4][2];
#pragma unroll
    for (int mt = 0; mt < 4; ++mt)
#pragma unroll
        for (int nq = 0; nq < 2; ++nq) o[mt][nq] = (float4v){0.f, 0.f, 0.f, 0.f};
    float lsum[2] = {0.f, 0.f};

    const int prow = w * 32 + lm;

#pragma unroll 2
    for (int t = 0; t < 32; ++t) {
        const int cur = t & 1;
        short* Kl = KV + cur * 8192;
        short* Vt = Kl + 4096;
        short* Kn = KV + (1 - cur) * 8192;
        short* Vn = Kn + 4096;

        __syncthreads();   // prev iter's reads of buf[!cur] done; buf[cur] writes visible

        if (t < 31) {      // stage tile t+1 into the other buffer
            *(short8*)(Kn + koff0) = kra;
            *(short8*)(Kn + koff1) = krb;
            *(short8*)(Vn + koff0) = vra;
            *(short8*)(Vn + koff1) = vrb;
        }
        if (t < 30) {      // prefetch tile t+2 (lands during next compute phase)
            kra = *(const short8*)(Kg + (size_t)((t + 2) * 64 + srow) * 64 + sc * 8);
            krb = *(const short8*)(Kg + (size_t)((t + 2) * 64 + srow + 32) * 64 + sc * 8);
            vra = *(const short8*)(Vg + (size_t)srow * L_ + (t + 2) * 64 + sc * 8);
            vrb = *(const short8*)(Vg + (size_t)(srow + 32) * L_ + (t + 2) * 64 + sc * 8);
        }

        // S^T = K Q^T : A = K rows (kpos), B = Q rows (qrow)
        float4v st[4][2];
#pragma unroll
        for (int nt = 0; nt < 4; ++nt) {
            short8 a0 = *(const short8*)(Kl + offA0[nt]);
            short8 a1 = *(const short8*)(Kl + offA1[nt]);
#pragma unroll
            for (int nq = 0; nq < 2; ++nq) {
                float4v z = (float4v){0.f, 0.f, 0.f, 0.f};
                z = __builtin_amdgcn_mfma_f32_16x16x32_bf16(a0, qf[nq][0], z, 0, 0, 0);
                z = __builtin_amdgcn_mfma_f32_16x16x32_bf16(a1, qf[nq][1], z, 0, 0, 0);
                st[nt][nq] = z;
            }
        }

        // exp2, per-lane row-sum partials, pack P^T -> Pt (v_perm trunc-bf16)
#pragma unroll
        for (int nt = 0; nt < 4; ++nt)
#pragma unroll
            for (int nq = 0; nq < 2; ++nq) {
                const float e0 = EXP2F(st[nt][nq][0]);
                const float e1 = EXP2F(st[nt][nq][1]);
                const float e2 = EXP2F(st[nt][nq][2]);
                const float e3 = EXP2F(st[nt][nq][3]);
                lsum[nq] += (e0 + e1) + (e2 + e3);
                uint2 pk;
                pk.x = pk_bf_trunc(e0, e1);
                pk.y = pk_bf_trunc(e2, e3);
                *(uint2*)(Pt + (prow + nq * 16) * 72 + nt * 16 + q * 4) = pk;
            }

        // O^T += V^T P^T : A = Vt rows (d), B = Pt rows (own wave's qrows)
#pragma unroll
        for (int kh = 0; kh < 2; ++kh) {
            short8 pb[2];
#pragma unroll
            for (int nq = 0; nq < 2; ++nq)
                pb[nq] = *(const short8*)(Pt + (prow + nq * 16) * 72 + kh * 32 + q * 8);
#pragma unroll
            for (int mt = 0; mt < 4; ++mt) {
                short8 va = *(const short8*)(Vt + offV[kh][mt]);
#pragma unroll
                for (int nq = 0; nq < 2; ++nq)
                    o[mt][nq] = __builtin_amdgcn_mfma_f32_16x16x32_bf16(va, pb[nq], o[mt][nq], 0, 0, 0);
            }
        }
    }

    // reduce row-sums across the 4 quads (same lm), normalize, store
    float inv[2];
#pragma unroll
    for (int nq = 0; nq < 2; ++nq) {
        float s = lsum[nq];
        s += __shfl_xor(s, 16);
        s += __shfl_xor(s, 32);
        inv[nq] = 1.f / s;
    }
    short* OgBase = Ob + ((size_t)bh * L_ + qt * 128) * HD_;
#pragma unroll
    for (int nq = 0; nq < 2; ++nq) {
        const int qrow = w * 32 + nq * 16 + lm;
#pragma unroll
        for (int mt = 0; mt < 4; ++mt) {
            short4v pk;
            pk.x = f2bf(o[mt][nq][0] * inv[nq]);
            pk.y = f2bf(o[mt][nq][1] * inv[nq]);
            pk.z = f2bf(o[mt][nq][2] * inv[nq]);
            pk.w = f2bf(o[mt][nq][3] * inv[nq]);
            *(short4v*)(OgBase + (size_t)qrow * 64 + mt * 16 + q * 4) = pk;
        }
    }
}

// ---------------------------------------------------------------------------
// Proj GEMM (bf16 MFMA): out[m,n] = sum_k O[m,k]*Wp[n,k], fp32 out.
// A read from [B,H,L,hd] (k = h*64+d). 64x128 tile, BK=32 -> 512 blocks.
// ---------------------------------------------------------------------------
__global__ __launch_bounds__(256) void gemm_proj_bf16(const short* __restrict__ Ob,
                                                      const short* __restrict__ Wp,
                                                      float* __restrict__ out) {
    __shared__ short As[64 * 32];
    __shared__ short Bs[128 * 32];
    const int tid = threadIdx.x;
    const int w = tid >> 6, l = tid & 63;
    const int lm = l & 15, q = l >> 4;
    const int m0 = blockIdx.y * 64, n0 = blockIdx.x * 128;
    const int wm = w & 1, wn = w >> 1;
    const int b = m0 >> 11, l0 = m0 & 2047;

    float4v acc[2][4];
#pragma unroll
    for (int mt = 0; mt < 2; ++mt)
#pragma unroll
        for (int nt = 0; nt < 4; ++nt) acc[mt][nt] = (float4v){0.f, 0.f, 0.f, 0.f};

    for (int k0 = 0; k0 < 1024; k0 += 32) {
        __syncthreads();
        {
            int idx8 = w * 64 + l;
            int row = idx8 >> 2, c8 = idx8 & 3;
            int h = k0 >> 6, d = (k0 & 32) + c8 * 8;
            gl_lds16(Ob + (((size_t)b * H_ + h) * L_ + l0 + row) * HD_ + d, (char*)As + w * 1024);
        }
#pragma unroll
        for (int t = 0; t < 2; ++t) {
            int idx8 = w * 128 + t * 64 + l;
            int row = idx8 >> 2, c8 = idx8 & 3;
            gl_lds16(Wp + (size_t)(n0 + row) * 1024 + k0 + c8 * 8, (char*)Bs + w * 2048 + t * 1024);
        }
        __syncthreads();
        short8 af[2], bfr[4];
#pragma unroll
        for (int mt = 0; mt < 2; ++mt)
            af[mt] = *(const short8*)(As + (wm * 32 + mt * 16 + lm) * 32 + q * 8);
#pragma unroll
        for (int nt = 0; nt < 4; ++nt)
            bfr[nt] = *(const short8*)(Bs + (wn * 64 + nt * 16 + lm) * 32 + q * 8);
#pragma unroll
        for (int mt = 0; mt < 2; ++mt)
#pragma unroll
            for (int nt = 0; nt < 4; ++nt)
                acc[mt][nt] = __builtin_amdgcn_mfma_f32_16x16x32_bf16(af[mt], bfr[nt], acc[mt][nt], 0, 0, 0);
    }

#pragma unroll
    for (int mt = 0; mt < 2; ++mt)
#pragma unroll
        for (int nt = 0; nt < 4; ++nt)
#pragma unroll
            for (int r = 0; r < 4; ++r) {
                const int m = m0 + wm * 32 + mt * 16 + q * 4 + r;
                const int n = n0 + wn * 64 + nt * 16 + lm;
                out[(size_t)m * 1024 + n] = acc[mt][nt][r];
            }
}

// ---------------------------------------------------------------------------
extern "C" void kernel_launch(void* const* d_in, const int* in_sizes, int n_in,
                              void* d_out, int out_size, void* d_ws, size_t ws_size,
                              hipStream_t stream) {
    (void)in_sizes; (void)n_in; (void)out_size; (void)ws_size;
    const float* x      = (const float*)d_in[0];
    const float* w_qkv  = (const float*)d_in[1];
    const float* w_proj = (const float*)d_in[2];

    char* ws = (char*)d_ws;                       // 40 MiB used
    short* Ob     = (short*)(ws);                 // 8 MiB  attention output [b,h,l,d]
    short* wqkvb  = (short*)(ws + (8u  << 20));   // 6 MiB
    short* wprojb = (short*)(ws + (14u << 20));   // 2 MiB
    short* Qb     = (short*)(ws + (16u << 20));   // 8 MiB  [b,h,l,d], scaled by 0.125*log2e
    short* Kb     = (short*)(ws + (24u << 20));   // 8 MiB  [b,h,l,d]
    short* Vb     = (short*)(ws + (32u << 20));   // 8 MiB  [b,h,d,kpos] (transposed!)

    cvt_w<<<4096, 256, 0, stream>>>(w_qkv, w_proj, wqkvb, wprojb);
    gemm_qkv_bf16 <<<dim3(24, 32), 256, 0, stream>>>(x, wqkvb, Qb, Kb, Vb);
    attn_mfma     <<<dim3(16, 32), 256, 0, stream>>>(Qb, Kb, Vb, Ob);
    gemm_proj_bf16<<<dim3(8, 64),  256, 0, stream>>>(Ob, wprojb, (float*)d_out);
}

// Round 6
// 198.113 us; speedup vs baseline: 1.0527x; 1.0527x over previous
//
#include <hip/hip_runtime.h>
#include <math.h>
#include <stdint.h>

// Problem constants
#define B_ 2
#define L_ 2048
#define D_ 1024
#define H_ 16
#define HD_ 64
// Q scale = 1/8 (softmax scale) * log2(e), folding exp->exp2
#define QSCALE_ 0.1803368801f

typedef __attribute__((ext_vector_type(8))) short short8;   // 8 bf16 = 4 VGPRs (MFMA A/B frag)
typedef __attribute__((ext_vector_type(4))) short short4v;
typedef __attribute__((ext_vector_type(4))) float float4v;  // MFMA C/D frag

#if defined(__has_builtin)
#if __has_builtin(__builtin_amdgcn_exp2f)
#define EXP2F(x) __builtin_amdgcn_exp2f(x)
#endif
#endif
#ifndef EXP2F
#define EXP2F(x) exp2f(x)
#endif

// fp32 -> bf16 round-to-nearest-even (bit pattern as short)
__device__ __forceinline__ short f2bf(float f) {
    union { float f; unsigned u; } x; x.f = f;
    unsigned r = x.u + 0x7fffu + ((x.u >> 16) & 1u);
    return (short)(r >> 16);
}

__device__ __forceinline__ unsigned fbits(float f) {
    union { float f; unsigned u; } x; x.f = f;
    return x.u;
}

// pack trunc-bf16(a) | trunc-bf16(b)<<16 in ONE v_perm_b32
__device__ __forceinline__ unsigned pk_bf_trunc(float a, float b) {
    return __builtin_amdgcn_perm(fbits(b), fbits(a), 0x07060302u);
}

// async global->LDS, 16B per lane. dst must be wave-uniform; HW writes dst + lane*16.
__device__ __forceinline__ void gl_lds16(const void* g, void* l) {
    __builtin_amdgcn_global_load_lds(
        (const __attribute__((address_space(1))) unsigned int*)g,
        (__attribute__((address_space(3))) unsigned int*)l, 16, 0, 0);
}

// ---------------------------------------------------------------------------
// Cast ALL inputs fp32->bf16 in one launch.
// x: 1048576 float4 groups; w_qkv: 786432; w_proj: 262144. Total 2097152.
// ---------------------------------------------------------------------------
__global__ __launch_bounds__(256) void cvt_all(const float* __restrict__ x,
                                               const float* __restrict__ wqkv,
                                               const float* __restrict__ wproj,
                                               short* __restrict__ xb,
                                               short* __restrict__ wqkvb,
                                               short* __restrict__ wprojb) {
    int i = blockIdx.x * 256 + threadIdx.x;   // grid 8192*256 = 2097152 exactly
    const float* in;
    short* out;
    int idx;
    if (i < 1048576)      { in = x;     out = xb;     idx = i; }
    else if (i < 1835008) { in = wqkv;  out = wqkvb;  idx = i - 1048576; }
    else                  { in = wproj; out = wprojb; idx = i - 1835008; }
    float4 v = ((const float4*)in)[idx];
    short4v o;
    o.x = f2bf(v.x); o.y = f2bf(v.y); o.z = f2bf(v.z); o.w = f2bf(v.w);
    ((short4v*)out)[idx] = o;
}

// ---------------------------------------------------------------------------
// QKV GEMM (bf16 MFMA): C[m,n] = sum_k X[m,k]*W[n,k]
// M=4096, N=3072, K=1024. 128x128 tile, BK=32, 4 waves 2x2, 4x4 16x16 tiles.
// 1D grid 768 with XCD swizzle: xcd = bid&7 sees only n-tiles {xcd, xcd+8,
// xcd+16} -> its W working set is 768 KB (fits 4 MB per-XCD L2).
// Q scattered [b,h,l,d] scaled by 0.125*log2e; K [b,h,l,d]; V^T [b,h,d,kpos].
// ---------------------------------------------------------------------------
__global__ __launch_bounds__(256) void gemm_qkv_bf16(const short* __restrict__ A,
                                                     const short* __restrict__ Bm,
                                                     short* __restrict__ Qb,
                                                     short* __restrict__ Kb,
                                                     short* __restrict__ Vb) {
    __shared__ short smem[8192];          // As = smem[0:4096], Bs = smem[4096:8192]
    short* As = smem;
    short* Bs = smem + 4096;
    const int tid = threadIdx.x;
    const int w = tid >> 6, l = tid & 63;
    const int lm = l & 15, q = l >> 4;
    // XCD swizzle: linear -> (m_tile, n_tile) s.t. same-XCD blocks share n-tiles
    const int bid = blockIdx.x;           // 0..767
    const int xcd = bid & 7;
    const int grp = bid >> 3;             // 0..95
    const int n_tile = xcd + 8 * (grp % 3);
    const int m_tile = grp / 3;
    const int m0 = m_tile * 128, n0 = n_tile * 128;
    const int wm = w >> 1, wn = w & 1;

    float4v acc[4][4];
#pragma unroll
    for (int mt = 0; mt < 4; ++mt)
#pragma unroll
        for (int nt = 0; nt < 4; ++nt) acc[mt][nt] = (float4v){0.f, 0.f, 0.f, 0.f};

    for (int k0 = 0; k0 < 1024; k0 += 32) {
        __syncthreads();
#pragma unroll
        for (int t = 0; t < 2; ++t) {
            int idx8 = w * 128 + t * 64 + l;
            int row = idx8 >> 2, c8 = idx8 & 3;
            gl_lds16(A  + (size_t)(m0 + row) * 1024 + k0 + c8 * 8, (char*)As + w * 2048 + t * 1024);
            gl_lds16(Bm + (size_t)(n0 + row) * 1024 + k0 + c8 * 8, (char*)Bs + w * 2048 + t * 1024);
        }
        __syncthreads();
        short8 af[4], bfr[4];
#pragma unroll
        for (int mt = 0; mt < 4; ++mt)
            af[mt] = *(const short8*)(As + (wm * 64 + mt * 16 + lm) * 32 + q * 8);
#pragma unroll
        for (int nt = 0; nt < 4; ++nt)
            bfr[nt] = *(const short8*)(Bs + (wn * 64 + nt * 16 + lm) * 32 + q * 8);
#pragma unroll
        for (int mt = 0; mt < 4; ++mt)
#pragma unroll
            for (int nt = 0; nt < 4; ++nt)
                acc[mt][nt] = __builtin_amdgcn_mfma_f32_16x16x32_bf16(af[mt], bfr[nt], acc[mt][nt], 0, 0, 0);
    }

    // C layout: col = lane&15, row = quad*4 + reg
    const int which = n0 >> 10;   // uniform per block: 0=Q, 1=K, 2=V
    if (which < 2) {
        short* dst = (which == 0) ? Qb : Kb;
        const float sc = (which == 0) ? QSCALE_ : 1.0f;
        // bounce through LDS in two 64-row halves for coalesced 16B stores
#pragma unroll
        for (int half = 0; half < 2; ++half) {
            __syncthreads();
            if (wm == half) {
#pragma unroll
                for (int mt = 0; mt < 4; ++mt)
#pragma unroll
                    for (int nt = 0; nt < 4; ++nt)
#pragma unroll
                        for (int r = 0; r < 4; ++r)
                            smem[(mt * 16 + q * 4 + r) * 128 + wn * 64 + nt * 16 + lm] =
                                f2bf(acc[mt][nt][r] * sc);
            }
            __syncthreads();
#pragma unroll
            for (int j = 0; j < 4; ++j) {
                const int x = tid + 256 * j;
                const int row = x >> 4, c = x & 15;
                short8 v = *(const short8*)(smem + row * 128 + c * 8);
                const int m = m0 + half * 64 + row;
                const int b = m >> 11, ll = m & 2047;
                const int n = n0 + c * 8;
                const int hh = (n & 1023) >> 6, d = n & 63;
                *(short8*)(dst + (((size_t)b * H_ + hh) * L_ + ll) * HD_ + d) = v;
            }
        }
    } else {
        // V^T: [b][h][d][kpos]; r indexes 4 consecutive kpos -> packed 8B store
#pragma unroll
        for (int mt = 0; mt < 4; ++mt) {
            const int m = m0 + wm * 64 + mt * 16 + q * 4;   // kpos base
            const int b = m >> 11, ll = m & 2047;
#pragma unroll
            for (int nt = 0; nt < 4; ++nt) {
                const int n = n0 + wn * 64 + nt * 16 + lm;
                const int h = (n & 1023) >> 6, d = n & 63;
                short4v pk;
                pk.x = f2bf(acc[mt][nt][0]); pk.y = f2bf(acc[mt][nt][1]);
                pk.z = f2bf(acc[mt][nt][2]); pk.w = f2bf(acc[mt][nt][3]);
                *(short4v*)(Vb + (((size_t)b * H_ + h) * HD_ + d) * L_ + ll) = pk;
            }
        }
    }
}

// ---------------------------------------------------------------------------
// Flash attention (unchanged from R4-best): block = 128 q-rows x (b,h);
// S^T = K Q^T, exp2, P packed via v_perm trunc-bf16, O^T = V^T P^T.
// K/V double-buffered, 1 barrier/iter; Q staged through Pt buffer.
// ---------------------------------------------------------------------------
__global__ __launch_bounds__(256) void attn_mfma(const short* __restrict__ Qb,
                                                 const short* __restrict__ Kb,
                                                 const short* __restrict__ Vtg,
                                                 short* __restrict__ Ob) {
    __shared__ short KV[4 * 4096];   // buf0: K,V ; buf1: K,V (each 64x64 swizzled)
    __shared__ short Pt[128 * 72];   // [qrow][kpos] stride 72; also Q staging area

    const int tid = threadIdx.x;
    const int w = tid >> 6, l = tid & 63;
    const int lm = l & 15, q = l >> 4;
    const int qt = blockIdx.x, bh = blockIdx.y;

    const short* Qg = Qb  + ((size_t)bh * L_ + qt * 128) * HD_;
    const short* Kg = Kb  + (size_t)bh * L_ * HD_;
    const short* Vg = Vtg + (size_t)bh * HD_ * L_;

    // ---- stage Q once into Pt (swizzled, stride 64); consumed into regs below ----
#pragma unroll
    for (int t = 0; t < 4; ++t) {
        int idx = tid + 256 * t;
        int row = idx >> 3, c = idx & 7;
        short8 v = *(const short8*)(Qg + row * 64 + c * 8);
        *(short8*)(Pt + row * 64 + ((c ^ (row & 7)) * 8)) = v;
    }

    // K/V staging geometry
    const int srow = tid >> 3;            // 0..31
    const int sc   = tid & 7;             // 0..7
    const int koff0 = srow * 64 + ((sc ^ (srow & 7)) * 8);
    const int koff1 = koff0 + 32 * 64;    // (srow+32)&7 == srow&7

    // tile 0 -> buf0 now; tile 1 -> regs
    {
        short8 ka = *(const short8*)(Kg + (size_t)srow * 64 + sc * 8);
        short8 kb = *(const short8*)(Kg + (size_t)(srow + 32) * 64 + sc * 8);
        short8 va = *(const short8*)(Vg + (size_t)srow * L_ + sc * 8);
        short8 vb = *(const short8*)(Vg + (size_t)(srow + 32) * L_ + sc * 8);
        *(short8*)(KV + koff0) = ka;
        *(short8*)(KV + koff1) = kb;
        *(short8*)(KV + 4096 + koff0) = va;
        *(short8*)(KV + 4096 + koff1) = vb;
    }
    short8 kra = *(const short8*)(Kg + (size_t)(64 + srow) * 64 + sc * 8);
    short8 krb = *(const short8*)(Kg + (size_t)(64 + srow + 32) * 64 + sc * 8);
    short8 vra = *(const short8*)(Vg + (size_t)srow * L_ + 64 + sc * 8);
    short8 vrb = *(const short8*)(Vg + (size_t)(srow + 32) * L_ + 64 + sc * 8);

    __syncthreads();   // Q + buf0 staged

    // Q fragments (loop-invariant, own 32 rows) -- read from Pt, then Pt is dead
    short8 qf[2][2];
#pragma unroll
    for (int nq = 0; nq < 2; ++nq)
#pragma unroll
        for (int kh = 0; kh < 2; ++kh) {
            int row = w * 32 + nq * 16 + lm;
            int ch = kh * 4 + q;
            qf[nq][kh] = *(const short8*)(Pt + row * 64 + ((ch ^ (row & 7)) * 8));
        }

    // hoisted frag offsets (iter-invariant)
    int offA0[4], offA1[4], offV[2][4];
#pragma unroll
    for (int nt = 0; nt < 4; ++nt) {
        const int arow = nt * 16 + lm;
        offA0[nt] = arow * 64 + ((q ^ (arow & 7)) * 8);
        offA1[nt] = arow * 64 + (((4 + q) ^ (arow & 7)) * 8);
#pragma unroll
        for (int kh = 0; kh < 2; ++kh)
            offV[kh][nt] = arow * 64 + (((kh * 4 + q) ^ (arow & 7)) * 8);
    }

    float4v o[4][2];
#pragma unroll
    for (int mt = 0; mt < 4; ++mt)
#pragma unroll
        for (int nq = 0; nq < 2; ++nq) o[mt][nq] = (float4v){0.f, 0.f, 0.f, 0.f};
    float lsum[2] = {0.f, 0.f};

    const int prow = w * 32 + lm;

#pragma unroll 2
    for (int t = 0; t < 32; ++t) {
        const int cur = t & 1;
        short* Kl = KV + cur * 8192;
        short* Vt = Kl + 4096;
        short* Kn = KV + (1 - cur) * 8192;
        short* Vn = Kn + 4096;

        __syncthreads();   // prev iter's reads of buf[!cur] done; buf[cur] writes visible

        if (t < 31) {      // stage tile t+1 into the other buffer
            *(short8*)(Kn + koff0) = kra;
            *(short8*)(Kn + koff1) = krb;
            *(short8*)(Vn + koff0) = vra;
            *(short8*)(Vn + koff1) = vrb;
        }
        if (t < 30) {      // prefetch tile t+2 (lands during next compute phase)
            kra = *(const short8*)(Kg + (size_t)((t + 2) * 64 + srow) * 64 + sc * 8);
            krb = *(const short8*)(Kg + (size_t)((t + 2) * 64 + srow + 32) * 64 + sc * 8);
            vra = *(const short8*)(Vg + (size_t)srow * L_ + (t + 2) * 64 + sc * 8);
            vrb = *(const short8*)(Vg + (size_t)(srow + 32) * L_ + (t + 2) * 64 + sc * 8);
        }

        // S^T = K Q^T : A = K rows (kpos), B = Q rows (qrow)
        float4v st[4][2];
#pragma unroll
        for (int nt = 0; nt < 4; ++nt) {
            short8 a0 = *(const short8*)(Kl + offA0[nt]);
            short8 a1 = *(const short8*)(Kl + offA1[nt]);
#pragma unroll
            for (int nq = 0; nq < 2; ++nq) {
                float4v z = (float4v){0.f, 0.f, 0.f, 0.f};
                z = __builtin_amdgcn_mfma_f32_16x16x32_bf16(a0, qf[nq][0], z, 0, 0, 0);
                z = __builtin_amdgcn_mfma_f32_16x16x32_bf16(a1, qf[nq][1], z, 0, 0, 0);
                st[nt][nq] = z;
            }
        }

        // exp2, per-lane row-sum partials, pack P^T -> Pt (v_perm trunc-bf16)
#pragma unroll
        for (int nt = 0; nt < 4; ++nt)
#pragma unroll
            for (int nq = 0; nq < 2; ++nq) {
                const float e0 = EXP2F(st[nt][nq][0]);
                const float e1 = EXP2F(st[nt][nq][1]);
                const float e2 = EXP2F(st[nt][nq][2]);
                const float e3 = EXP2F(st[nt][nq][3]);
                lsum[nq] += (e0 + e1) + (e2 + e3);
                uint2 pk;
                pk.x = pk_bf_trunc(e0, e1);
                pk.y = pk_bf_trunc(e2, e3);
                *(uint2*)(Pt + (prow + nq * 16) * 72 + nt * 16 + q * 4) = pk;
            }

        // O^T += V^T P^T : A = Vt rows (d), B = Pt rows (own wave's qrows)
#pragma unroll
        for (int kh = 0; kh < 2; ++kh) {
            short8 pb[2];
#pragma unroll
            for (int nq = 0; nq < 2; ++nq)
                pb[nq] = *(const short8*)(Pt + (prow + nq * 16) * 72 + kh * 32 + q * 8);
#pragma unroll
            for (int mt = 0; mt < 4; ++mt) {
                short8 va = *(const short8*)(Vt + offV[kh][mt]);
#pragma unroll
                for (int nq = 0; nq < 2; ++nq)
                    o[mt][nq] = __builtin_amdgcn_mfma_f32_16x16x32_bf16(va, pb[nq], o[mt][nq], 0, 0, 0);
            }
        }
    }

    // reduce row-sums across the 4 quads (same lm), normalize, store
    float inv[2];
#pragma unroll
    for (int nq = 0; nq < 2; ++nq) {
        float s = lsum[nq];
        s += __shfl_xor(s, 16);
        s += __shfl_xor(s, 32);
        inv[nq] = 1.f / s;
    }
    short* OgBase = Ob + ((size_t)bh * L_ + qt * 128) * HD_;
#pragma unroll
    for (int nq = 0; nq < 2; ++nq) {
        const int qrow = w * 32 + nq * 16 + lm;
#pragma unroll
        for (int mt = 0; mt < 4; ++mt) {
            short4v pk;
            pk.x = f2bf(o[mt][nq][0] * inv[nq]);
            pk.y = f2bf(o[mt][nq][1] * inv[nq]);
            pk.z = f2bf(o[mt][nq][2] * inv[nq]);
            pk.w = f2bf(o[mt][nq][3] * inv[nq]);
            *(short4v*)(OgBase + (size_t)qrow * 64 + mt * 16 + q * 4) = pk;
        }
    }
}

// ---------------------------------------------------------------------------
// Proj GEMM (bf16 MFMA): out[m,n] = sum_k O[m,k]*Wp[n,k], fp32 out.
// A read from [B,H,L,hd] (k = h*64+d). 64x128 tile, BK=32.
// 1D grid 512 with XCD swizzle: n_tile = bid&7 -> each XCD reads ONE 256 KB
// W strip (L2-resident).
// ---------------------------------------------------------------------------
__global__ __launch_bounds__(256) void gemm_proj_bf16(const short* __restrict__ Ob,
                                                      const short* __restrict__ Wp,
                                                      float* __restrict__ out) {
    __shared__ short As[64 * 32];
    __shared__ short Bs[128 * 32];
    const int tid = threadIdx.x;
    const int w = tid >> 6, l = tid & 63;
    const int lm = l & 15, q = l >> 4;
    const int bid = blockIdx.x;           // 0..511
    const int m0 = (bid >> 3) * 64, n0 = (bid & 7) * 128;
    const int wm = w & 1, wn = w >> 1;
    const int b = m0 >> 11, l0 = m0 & 2047;

    float4v acc[2][4];
#pragma unroll
    for (int mt = 0; mt < 2; ++mt)
#pragma unroll
        for (int nt = 0; nt < 4; ++nt) acc[mt][nt] = (float4v){0.f, 0.f, 0.f, 0.f};

    for (int k0 = 0; k0 < 1024; k0 += 32) {
        __syncthreads();
        {
            int idx8 = w * 64 + l;
            int row = idx8 >> 2, c8 = idx8 & 3;
            int h = k0 >> 6, d = (k0 & 32) + c8 * 8;
            gl_lds16(Ob + (((size_t)b * H_ + h) * L_ + l0 + row) * HD_ + d, (char*)As + w * 1024);
        }
#pragma unroll
        for (int t = 0; t < 2; ++t) {
            int idx8 = w * 128 + t * 64 + l;
            int row = idx8 >> 2, c8 = idx8 & 3;
            gl_lds16(Wp + (size_t)(n0 + row) * 1024 + k0 + c8 * 8, (char*)Bs + w * 2048 + t * 1024);
        }
        __syncthreads();
        short8 af[2], bfr[4];
#pragma unroll
        for (int mt = 0; mt < 2; ++mt)
            af[mt] = *(const short8*)(As + (wm * 32 + mt * 16 + lm) * 32 + q * 8);
#pragma unroll
        for (int nt = 0; nt < 4; ++nt)
            bfr[nt] = *(const short8*)(Bs + (wn * 64 + nt * 16 + lm) * 32 + q * 8);
#pragma unroll
        for (int mt = 0; mt < 2; ++mt)
#pragma unroll
            for (int nt = 0; nt < 4; ++nt)
                acc[mt][nt] = __builtin_amdgcn_mfma_f32_16x16x32_bf16(af[mt], bfr[nt], acc[mt][nt], 0, 0, 0);
    }

#pragma unroll
    for (int mt = 0; mt < 2; ++mt)
#pragma unroll
        for (int nt = 0; nt < 4; ++nt)
#pragma unroll
            for (int r = 0; r < 4; ++r) {
                const int m = m0 + wm * 32 + mt * 16 + q * 4 + r;
                const int n = n0 + wn * 64 + nt * 16 + lm;
                out[(size_t)m * 1024 + n] = acc[mt][nt][r];
            }
}

// ---------------------------------------------------------------------------
extern "C" void kernel_launch(void* const* d_in, const int* in_sizes, int n_in,
                              void* d_out, int out_size, void* d_ws, size_t ws_size,
                              hipStream_t stream) {
    (void)in_sizes; (void)n_in; (void)out_size; (void)ws_size;
    const float* x      = (const float*)d_in[0];
    const float* w_qkv  = (const float*)d_in[1];
    const float* w_proj = (const float*)d_in[2];

    char* ws = (char*)d_ws;                       // 48 MiB used
    short* xb     = (short*)(ws);                 // 8 MiB (reused as Ob after qkv)
    short* wqkvb  = (short*)(ws + (8u  << 20));   // 6 MiB
    short* wprojb = (short*)(ws + (14u << 20));   // 2 MiB
    short* Qb     = (short*)(ws + (16u << 20));   // 8 MiB  [b,h,l,d], scaled 0.125*log2e
    short* Kb     = (short*)(ws + (24u << 20));   // 8 MiB  [b,h,l,d]
    short* Vb     = (short*)(ws + (32u << 20));   // 8 MiB  [b,h,d,kpos] (transposed!)
    short* Ob     = (short*)(ws + (40u << 20));   // 8 MiB  attention output [b,h,l,d]

    cvt_all<<<8192, 256, 0, stream>>>(x, w_qkv, w_proj, xb, wqkvb, wprojb);
    gemm_qkv_bf16 <<<768, 256, 0, stream>>>(xb, wqkvb, Qb, Kb, Vb);
    attn_mfma     <<<dim3(16, 32), 256, 0, stream>>>(Qb, Kb, Vb, Ob);
    gemm_proj_bf16<<<512, 256, 0, stream>>>(Ob, wprojb, (float*)d_out);
}

// Round 8
// 194.125 us; speedup vs baseline: 1.0743x; 1.0205x over previous
//
#include <hip/hip_runtime.h>
#include <math.h>
#include <stdint.h>

// Problem constants
#define B_ 2
#define L_ 2048
#define D_ 1024
#define H_ 16
#define HD_ 64
// Q scale = 1/8 (softmax scale) * log2(e), folding exp->exp2
#define QSCALE_ 0.1803368801f

typedef __attribute__((ext_vector_type(8))) short short8;   // 8 bf16 = 4 VGPRs (MFMA A/B frag)
typedef __attribute__((ext_vector_type(4))) short short4v;
typedef __attribute__((ext_vector_type(4))) float float4v;  // MFMA C/D frag

#if defined(__has_builtin)
#if __has_builtin(__builtin_amdgcn_exp2f)
#define EXP2F(x) __builtin_amdgcn_exp2f(x)
#endif
#endif
#ifndef EXP2F
#define EXP2F(x) exp2f(x)
#endif

// fp32 -> bf16 round-to-nearest-even (bit pattern as short)
__device__ __forceinline__ short f2bf(float f) {
    union { float f; unsigned u; } x; x.f = f;
    unsigned r = x.u + 0x7fffu + ((x.u >> 16) & 1u);
    return (short)(r >> 16);
}

__device__ __forceinline__ unsigned fbits(float f) {
    union { float f; unsigned u; } x; x.f = f;
    return x.u;
}

// pack trunc-bf16(a) | trunc-bf16(b)<<16 in ONE v_perm_b32
__device__ __forceinline__ unsigned pk_bf_trunc(float a, float b) {
    return __builtin_amdgcn_perm(fbits(b), fbits(a), 0x07060302u);
}

// async global->LDS, 16B per lane. dst must be wave-uniform; HW writes dst + lane*16.
__device__ __forceinline__ void gl_lds16(const void* g, void* l) {
    __builtin_amdgcn_global_load_lds(
        (const __attribute__((address_space(1))) unsigned int*)g,
        (__attribute__((address_space(3))) unsigned int*)l, 16, 0, 0);
}

// ---------------------------------------------------------------------------
// Cast ALL inputs fp32->bf16 in one launch.
// x: 1048576 float4 groups; w_qkv: 786432; w_proj: 262144. Total 2097152.
// ---------------------------------------------------------------------------
__global__ __launch_bounds__(256) void cvt_all(const float* __restrict__ x,
                                               const float* __restrict__ wqkv,
                                               const float* __restrict__ wproj,
                                               short* __restrict__ xb,
                                               short* __restrict__ wqkvb,
                                               short* __restrict__ wprojb) {
    int i = blockIdx.x * 256 + threadIdx.x;   // grid 8192*256 = 2097152 exactly
    const float* in;
    short* out;
    int idx;
    if (i < 1048576)      { in = x;     out = xb;     idx = i; }
    else if (i < 1835008) { in = wqkv;  out = wqkvb;  idx = i - 1048576; }
    else                  { in = wproj; out = wprojb; idx = i - 1835008; }
    float4 v = ((const float4*)in)[idx];
    short4v o;
    o.x = f2bf(v.x); o.y = f2bf(v.y); o.z = f2bf(v.z); o.w = f2bf(v.w);
    ((short4v*)out)[idx] = o;
}

// ---------------------------------------------------------------------------
// QKV GEMM (bf16 MFMA): C[m,n] = sum_k X[m,k]*W[n,k]
// M=4096, N=3072, K=1024. 128x128 tile, BK=64 as TWO 32-sub-tiles (keeps the
// conflict-free gl_lds16 layout; halves barrier count vs BK=32).
// 1D grid 768 with XCD swizzle: xcd = bid&7 sees only n-tiles {xcd, xcd+8,
// xcd+16} -> W working set 768 KB (fits 4 MB per-XCD L2).
// Q scattered [b,h,l,d] scaled by 0.125*log2e; K [b,h,l,d]; V^T [b,h,d,kpos].
// ---------------------------------------------------------------------------
__global__ __launch_bounds__(256) void gemm_qkv_bf16(const short* __restrict__ A,
                                                     const short* __restrict__ Bm,
                                                     short* __restrict__ Qb,
                                                     short* __restrict__ Kb,
                                                     short* __restrict__ Vb) {
    __shared__ short smem[16384];         // As = smem[0:8192], Bs = smem[8192:16384]
    short* As = smem;                     // [half][128 rows][32 k], half stride 4096
    short* Bs = smem + 8192;
    const int tid = threadIdx.x;
    const int w = tid >> 6, l = tid & 63;
    const int lm = l & 15, q = l >> 4;
    // XCD swizzle: linear -> (m_tile, n_tile) s.t. same-XCD blocks share n-tiles
    const int bid = blockIdx.x;           // 0..767
    const int xcd = bid & 7;
    const int grp = bid >> 3;             // 0..95
    const int n_tile = xcd + 8 * (grp % 3);
    const int m_tile = grp / 3;
    const int m0 = m_tile * 128, n0 = n_tile * 128;
    const int wm = w >> 1, wn = w & 1;

    float4v acc[4][4];
#pragma unroll
    for (int mt = 0; mt < 4; ++mt)
#pragma unroll
        for (int nt = 0; nt < 4; ++nt) acc[mt][nt] = (float4v){0.f, 0.f, 0.f, 0.f};

    for (int k0 = 0; k0 < 1024; k0 += 64) {
        __syncthreads();
#pragma unroll
        for (int h = 0; h < 2; ++h) {
#pragma unroll
            for (int t = 0; t < 2; ++t) {
                int idx8 = w * 128 + t * 64 + l;
                int row = idx8 >> 2, c8 = idx8 & 3;
                gl_lds16(A  + (size_t)(m0 + row) * 1024 + k0 + h * 32 + c8 * 8,
                         (char*)As + h * 8192 + w * 2048 + t * 1024);
                gl_lds16(Bm + (size_t)(n0 + row) * 1024 + k0 + h * 32 + c8 * 8,
                         (char*)Bs + h * 8192 + w * 2048 + t * 1024);
            }
        }
        __syncthreads();
#pragma unroll
        for (int h = 0; h < 2; ++h) {
            short8 af[4], bfr[4];
#pragma unroll
            for (int mt = 0; mt < 4; ++mt)
                af[mt] = *(const short8*)(As + h * 4096 + (wm * 64 + mt * 16 + lm) * 32 + q * 8);
#pragma unroll
            for (int nt = 0; nt < 4; ++nt)
                bfr[nt] = *(const short8*)(Bs + h * 4096 + (wn * 64 + nt * 16 + lm) * 32 + q * 8);
#pragma unroll
            for (int mt = 0; mt < 4; ++mt)
#pragma unroll
                for (int nt = 0; nt < 4; ++nt)
                    acc[mt][nt] = __builtin_amdgcn_mfma_f32_16x16x32_bf16(af[mt], bfr[nt], acc[mt][nt], 0, 0, 0);
        }
    }

    // C layout: col = lane&15, row = quad*4 + reg
    const int which = n0 >> 10;   // uniform per block: 0=Q, 1=K, 2=V
    if (which < 2) {
        short* dst = (which == 0) ? Qb : Kb;
        const float sc = (which == 0) ? QSCALE_ : 1.0f;
        // bounce through LDS in two 64-row halves for coalesced 16B stores
#pragma unroll
        for (int half = 0; half < 2; ++half) {
            __syncthreads();
            if (wm == half) {
#pragma unroll
                for (int mt = 0; mt < 4; ++mt)
#pragma unroll
                    for (int nt = 0; nt < 4; ++nt)
#pragma unroll
                        for (int r = 0; r < 4; ++r)
                            smem[(mt * 16 + q * 4 + r) * 128 + wn * 64 + nt * 16 + lm] =
                                f2bf(acc[mt][nt][r] * sc);
            }
            __syncthreads();
#pragma unroll
            for (int j = 0; j < 4; ++j) {
                const int x = tid + 256 * j;
                const int row = x >> 4, c = x & 15;
                short8 v = *(const short8*)(smem + row * 128 + c * 8);
                const int m = m0 + half * 64 + row;
                const int b = m >> 11, ll = m & 2047;
                const int n = n0 + c * 8;
                const int hh = (n & 1023) >> 6, d = n & 63;
                *(short8*)(dst + (((size_t)b * H_ + hh) * L_ + ll) * HD_ + d) = v;
            }
        }
    } else {
        // V^T: [b][h][d][kpos]; r indexes 4 consecutive kpos -> packed 8B store
#pragma unroll
        for (int mt = 0; mt < 4; ++mt) {
            const int m = m0 + wm * 64 + mt * 16 + q * 4;   // kpos base
            const int b = m >> 11, ll = m & 2047;
#pragma unroll
            for (int nt = 0; nt < 4; ++nt) {
                const int n = n0 + wn * 64 + nt * 16 + lm;
                const int h = (n & 1023) >> 6, d = n & 63;
                short4v pk;
                pk.x = f2bf(acc[mt][nt][0]); pk.y = f2bf(acc[mt][nt][1]);
                pk.z = f2bf(acc[mt][nt][2]); pk.w = f2bf(acc[mt][nt][3]);
                *(short4v*)(Vb + (((size_t)b * H_ + h) * HD_ + d) * L_ + ll) = pk;
            }
        }
    }
}

// ---------------------------------------------------------------------------
// Flash attention v4 (REVERTED, replay-proven): block = 128 q-rows x (b,h);
// S^T = K Q^T, exp2, P packed via v_perm trunc-bf16, O^T = V^T P^T.
// K/V double-buffered, 1 barrier/iter; Q staged through Pt buffer.
// ---------------------------------------------------------------------------
__global__ __launch_bounds__(256) void attn_mfma(const short* __restrict__ Qb,
                                                 const short* __restrict__ Kb,
                                                 const short* __restrict__ Vtg,
                                                 short* __restrict__ Ob) {
    __shared__ short KV[4 * 4096];   // buf0: K,V ; buf1: K,V (each 64x64 swizzled)
    __shared__ short Pt[128 * 72];   // [qrow][kpos] stride 72; also Q staging area

    const int tid = threadIdx.x;
    const int w = tid >> 6, l = tid & 63;
    const int lm = l & 15, q = l >> 4;
    const int qt = blockIdx.x, bh = blockIdx.y;

    const short* Qg = Qb  + ((size_t)bh * L_ + qt * 128) * HD_;
    const short* Kg = Kb  + (size_t)bh * L_ * HD_;
    const short* Vg = Vtg + (size_t)bh * HD_ * L_;

    // ---- stage Q once into Pt (swizzled, stride 64); consumed into regs below ----
#pragma unroll
    for (int t = 0; t < 4; ++t) {
        int idx = tid + 256 * t;
        int row = idx >> 3, c = idx & 7;
        short8 v = *(const short8*)(Qg + row * 64 + c * 8);
        *(short8*)(Pt + row * 64 + ((c ^ (row & 7)) * 8)) = v;
    }

    // K/V staging geometry
    const int srow = tid >> 3;            // 0..31
    const int sc   = tid & 7;             // 0..7
    const int koff0 = srow * 64 + ((sc ^ (srow & 7)) * 8);
    const int koff1 = koff0 + 32 * 64;    // (srow+32)&7 == srow&7

    // tile 0 -> buf0 now; tile 1 -> regs
    {
        short8 ka = *(const short8*)(Kg + (size_t)srow * 64 + sc * 8);
        short8 kb = *(const short8*)(Kg + (size_t)(srow + 32) * 64 + sc * 8);
        short8 va = *(const short8*)(Vg + (size_t)srow * L_ + sc * 8);
        short8 vb = *(const short8*)(Vg + (size_t)(srow + 32) * L_ + sc * 8);
        *(short8*)(KV + koff0) = ka;
        *(short8*)(KV + koff1) = kb;
        *(short8*)(KV + 4096 + koff0) = va;
        *(short8*)(KV + 4096 + koff1) = vb;
    }
    short8 kra = *(const short8*)(Kg + (size_t)(64 + srow) * 64 + sc * 8);
    short8 krb = *(const short8*)(Kg + (size_t)(64 + srow + 32) * 64 + sc * 8);
    short8 vra = *(const short8*)(Vg + (size_t)srow * L_ + 64 + sc * 8);
    short8 vrb = *(const short8*)(Vg + (size_t)(srow + 32) * L_ + 64 + sc * 8);

    __syncthreads();   // Q + tile0 staged

    // Q fragments (loop-invariant, own 32 rows) -- read from Pt, then Pt is dead
    short8 qf[2][2];
#pragma unroll
    for (int nq = 0; nq < 2; ++nq)
#pragma unroll
        for (int kh = 0; kh < 2; ++kh) {
            int row = w * 32 + nq * 16 + lm;
            int ch = kh * 4 + q;
            qf[nq][kh] = *(const short8*)(Pt + row * 64 + ((ch ^ (row & 7)) * 8));
        }

    // hoisted frag offsets (iter-invariant)
    int offA0[4], offA1[4], offV[2][4];
#pragma unroll
    for (int nt = 0; nt < 4; ++nt) {
        const int arow = nt * 16 + lm;
        offA0[nt] = arow * 64 + ((q ^ (arow & 7)) * 8);
        offA1[nt] = arow * 64 + (((4 + q) ^ (arow & 7)) * 8);
#pragma unroll
        for (int kh = 0; kh < 2; ++kh)
            offV[kh][nt] = arow * 64 + (((kh * 4 + q) ^ (arow & 7)) * 8);
    }

    float4v o[4][2];
#pragma unroll
    for (int mt = 0; mt < 4; ++mt)
#pragma unroll
        for (int nq = 0; nq < 2; ++nq) o[mt][nq] = (float4v){0.f, 0.f, 0.f, 0.f};
    float lsum[2] = {0.f, 0.f};

    const int prow = w * 32 + lm;

#pragma unroll 2
    for (int t = 0; t < 32; ++t) {
        const int cur = t & 1;
        short* Kl = KV + cur * 8192;
        short* Vt = Kl + 4096;
        short* Kn = KV + (1 - cur) * 8192;
        short* Vn = Kn + 4096;

        __syncthreads();   // prev iter's reads of buf[!cur] done; buf[cur] writes visible

        if (t < 31) {      // stage tile t+1 into the other buffer
            *(short8*)(Kn + koff0) = kra;
            *(short8*)(Kn + koff1) = krb;
            *(short8*)(Vn + koff0) = vra;
            *(short8*)(Vn + koff1) = vrb;
        }
        if (t < 30) {      // prefetch tile t+2 (lands during next compute phase)
            kra = *(const short8*)(Kg + (size_t)((t + 2) * 64 + srow) * 64 + sc * 8);
            krb = *(const short8*)(Kg + (size_t)((t + 2) * 64 + srow + 32) * 64 + sc * 8);
            vra = *(const short8*)(Vg + (size_t)srow * L_ + (t + 2) * 64 + sc * 8);
            vrb = *(const short8*)(Vg + (size_t)(srow + 32) * L_ + (t + 2) * 64 + sc * 8);
        }

        // S^T = K Q^T : A = K rows (kpos), B = Q rows (qrow)
        float4v st[4][2];
#pragma unroll
        for (int nt = 0; nt < 4; ++nt) {
            short8 a0 = *(const short8*)(Kl + offA0[nt]);
            short8 a1 = *(const short8*)(Kl + offA1[nt]);
#pragma unroll
            for (int nq = 0; nq < 2; ++nq) {
                float4v z = (float4v){0.f, 0.f, 0.f, 0.f};
                z = __builtin_amdgcn_mfma_f32_16x16x32_bf16(a0, qf[nq][0], z, 0, 0, 0);
                z = __builtin_amdgcn_mfma_f32_16x16x32_bf16(a1, qf[nq][1], z, 0, 0, 0);
                st[nt][nq] = z;
            }
        }

        // exp2, per-lane row-sum partials, pack P^T -> Pt (v_perm trunc-bf16)
#pragma unroll
        for (int nt = 0; nt < 4; ++nt)
#pragma unroll
            for (int nq = 0; nq < 2; ++nq) {
                const float e0 = EXP2F(st[nt][nq][0]);
                const float e1 = EXP2F(st[nt][nq][1]);
                const float e2 = EXP2F(st[nt][nq][2]);
                const float e3 = EXP2F(st[nt][nq][3]);
                lsum[nq] += (e0 + e1) + (e2 + e3);
                uint2 pk;
                pk.x = pk_bf_trunc(e0, e1);
                pk.y = pk_bf_trunc(e2, e3);
                *(uint2*)(Pt + (prow + nq * 16) * 72 + nt * 16 + q * 4) = pk;
            }

        // O^T += V^T P^T : A = Vt rows (d), B = Pt rows (own wave's qrows)
#pragma unroll
        for (int kh = 0; kh < 2; ++kh) {
            short8 pb[2];
#pragma unroll
            for (int nq = 0; nq < 2; ++nq)
                pb[nq] = *(const short8*)(Pt + (prow + nq * 16) * 72 + kh * 32 + q * 8);
#pragma unroll
            for (int mt = 0; mt < 4; ++mt) {
                short8 va = *(const short8*)(Vt + offV[kh][mt]);
#pragma unroll
                for (int nq = 0; nq < 2; ++nq)
                    o[mt][nq] = __builtin_amdgcn_mfma_f32_16x16x32_bf16(va, pb[nq], o[mt][nq], 0, 0, 0);
            }
        }
    }

    // reduce row-sums across the 4 quads (same lm), normalize, store
    float inv[2];
#pragma unroll
    for (int nq = 0; nq < 2; ++nq) {
        float s = lsum[nq];
        s += __shfl_xor(s, 16);
        s += __shfl_xor(s, 32);
        inv[nq] = 1.f / s;
    }
    short* OgBase = Ob + ((size_t)bh * L_ + qt * 128) * HD_;
#pragma unroll
    for (int nq = 0; nq < 2; ++nq) {
        const int qrow = w * 32 + nq * 16 + lm;
#pragma unroll
        for (int mt = 0; mt < 4; ++mt) {
            short4v pk;
            pk.x = f2bf(o[mt][nq][0] * inv[nq]);
            pk.y = f2bf(o[mt][nq][1] * inv[nq]);
            pk.z = f2bf(o[mt][nq][2] * inv[nq]);
            pk.w = f2bf(o[mt][nq][3] * inv[nq]);
            *(short4v*)(OgBase + (size_t)qrow * 64 + mt * 16 + q * 4) = pk;
        }
    }
}

// ---------------------------------------------------------------------------
// Proj GEMM (bf16 MFMA): out[m,n] = sum_k O[m,k]*Wp[n,k], fp32 out.
// A read from [B,H,L,hd] (k = h*64+d; k0 is 64-aligned -> one head per iter).
// 64x128 tile, BK=64 as two 32-sub-tiles. 1D grid 512 with XCD swizzle:
// n_tile = bid&7 -> each XCD reads ONE 256 KB W strip (L2-resident).
// ---------------------------------------------------------------------------
__global__ __launch_bounds__(256) void gemm_proj_bf16(const short* __restrict__ Ob,
                                                      const short* __restrict__ Wp,
                                                      float* __restrict__ out) {
    __shared__ short As[2 * 2048];   // [half][64 rows][32 k]
    __shared__ short Bs[2 * 4096];   // [half][128 rows][32 k]
    const int tid = threadIdx.x;
    const int w = tid >> 6, l = tid & 63;
    const int lm = l & 15, q = l >> 4;
    const int bid = blockIdx.x;           // 0..511
    const int m0 = (bid >> 3) * 64, n0 = (bid & 7) * 128;
    const int wm = w & 1, wn = w >> 1;
    const int b = m0 >> 11, l0 = m0 & 2047;

    float4v acc[2][4];
#pragma unroll
    for (int mt = 0; mt < 2; ++mt)
#pragma unroll
        for (int nt = 0; nt < 4; ++nt) acc[mt][nt] = (float4v){0.f, 0.f, 0.f, 0.f};

    for (int k0 = 0; k0 < 1024; k0 += 64) {
        const int hh = k0 >> 6;   // head index, uniform per iter
        __syncthreads();
#pragma unroll
        for (int h = 0; h < 2; ++h) {
            {
                int idx8 = w * 64 + l;
                int row = idx8 >> 2, c8 = idx8 & 3;
                gl_lds16(Ob + (((size_t)b * H_ + hh) * L_ + l0 + row) * HD_ + h * 32 + c8 * 8,
                         (char*)As + h * 4096 + w * 1024);
            }
#pragma unroll
            for (int t = 0; t < 2; ++t) {
                int idx8 = w * 128 + t * 64 + l;
                int row = idx8 >> 2, c8 = idx8 & 3;
                gl_lds16(Wp + (size_t)(n0 + row) * 1024 + k0 + h * 32 + c8 * 8,
                         (char*)Bs + h * 8192 + w * 2048 + t * 1024);
            }
        }
        __syncthreads();
#pragma unroll
        for (int h = 0; h < 2; ++h) {
            short8 af[2], bfr[4];
#pragma unroll
            for (int mt = 0; mt < 2; ++mt)
                af[mt] = *(const short8*)(As + h * 2048 + (wm * 32 + mt * 16 + lm) * 32 + q * 8);
#pragma unroll
            for (int nt = 0; nt < 4; ++nt)
                bfr[nt] = *(const short8*)(Bs + h * 4096 + (wn * 64 + nt * 16 + lm) * 32 + q * 8);
#pragma unroll
            for (int mt = 0; mt < 2; ++mt)
#pragma unroll
                for (int nt = 0; nt < 4; ++nt)
                    acc[mt][nt] = __builtin_amdgcn_mfma_f32_16x16x32_bf16(af[mt], bfr[nt], acc[mt][nt], 0, 0, 0);
        }
    }

#pragma unroll
    for (int mt = 0; mt < 2; ++mt)
#pragma unroll
        for (int nt = 0; nt < 4; ++nt)
#pragma unroll
            for (int r = 0; r < 4; ++r) {
                const int m = m0 + wm * 32 + mt * 16 + q * 4 + r;
                const int n = n0 + wn * 64 + nt * 16 + lm;
                out[(size_t)m * 1024 + n] = acc[mt][nt][r];
            }
}

// ---------------------------------------------------------------------------
extern "C" void kernel_launch(void* const* d_in, const int* in_sizes, int n_in,
                              void* d_out, int out_size, void* d_ws, size_t ws_size,
                              hipStream_t stream) {
    (void)in_sizes; (void)n_in; (void)out_size; (void)ws_size;
    const float* x      = (const float*)d_in[0];
    const float* w_qkv  = (const float*)d_in[1];
    const float* w_proj = (const float*)d_in[2];

    char* ws = (char*)d_ws;                       // 48 MiB used
    short* xb     = (short*)(ws);                 // 8 MiB
    short* wqkvb  = (short*)(ws + (8u  << 20));   // 6 MiB
    short* wprojb = (short*)(ws + (14u << 20));   // 2 MiB
    short* Qb     = (short*)(ws + (16u << 20));   // 8 MiB  [b,h,l,d], scaled 0.125*log2e
    short* Kb     = (short*)(ws + (24u << 20));   // 8 MiB  [b,h,l,d]
    short* Vb     = (short*)(ws + (32u << 20));   // 8 MiB  [b,h,d,kpos] (transposed!)
    short* Ob     = (short*)(ws + (40u << 20));   // 8 MiB  attention output [b,h,l,d]

    cvt_all<<<8192, 256, 0, stream>>>(x, w_qkv, w_proj, xb, wqkvb, wprojb);
    gemm_qkv_bf16 <<<768, 256, 0, stream>>>(xb, wqkvb, Qb, Kb, Vb);
    attn_mfma     <<<dim3(16, 32), 256, 0, stream>>>(Qb, Kb, Vb, Ob);
    gemm_proj_bf16<<<512, 256, 0, stream>>>(Ob, wprojb, (float*)d_out);
}

// Round 9
// 192.428 us; speedup vs baseline: 1.0838x; 1.0088x over previous
//
#include <hip/hip_runtime.h>
#include <math.h>
#include <stdint.h>

// Problem constants
#define B_ 2
#define L_ 2048
#define D_ 1024
#define H_ 16
#define HD_ 64
// Q scale = 1/8 (softmax scale) * log2(e), folding exp->exp2
#define QSCALE_ 0.1803368801f

typedef __attribute__((ext_vector_type(8))) short short8;   // 8 bf16 = 4 VGPRs (MFMA A/B frag)
typedef __attribute__((ext_vector_type(4))) short short4v;
typedef __attribute__((ext_vector_type(4))) float float4v;  // MFMA C/D frag

#if defined(__has_builtin)
#if __has_builtin(__builtin_amdgcn_exp2f)
#define EXP2F(x) __builtin_amdgcn_exp2f(x)
#endif
#endif
#ifndef EXP2F
#define EXP2F(x) exp2f(x)
#endif

// fp32 -> bf16 round-to-nearest-even (bit pattern as short)
__device__ __forceinline__ short f2bf(float f) {
    union { float f; unsigned u; } x; x.f = f;
    unsigned r = x.u + 0x7fffu + ((x.u >> 16) & 1u);
    return (short)(r >> 16);
}

__device__ __forceinline__ unsigned fbits(float f) {
    union { float f; unsigned u; } x; x.f = f;
    return x.u;
}

// pack trunc-bf16(a) | trunc-bf16(b)<<16 in ONE v_perm_b32
__device__ __forceinline__ unsigned pk_bf_trunc(float a, float b) {
    return __builtin_amdgcn_perm(fbits(b), fbits(a), 0x07060302u);
}

// async global->LDS, 16B per lane. dst must be wave-uniform; HW writes dst + lane*16.
__device__ __forceinline__ void gl_lds16(const void* g, void* l) {
    __builtin_amdgcn_global_load_lds(
        (const __attribute__((address_space(1))) unsigned int*)g,
        (__attribute__((address_space(3))) unsigned int*)l, 16, 0, 0);
}

// ---------------------------------------------------------------------------
// Cast ALL inputs fp32->bf16 in one launch.
// x: 1048576 float4 groups; w_qkv: 786432; w_proj: 262144. Total 2097152.
// ---------------------------------------------------------------------------
__global__ __launch_bounds__(256) void cvt_all(const float* __restrict__ x,
                                               const float* __restrict__ wqkv,
                                               const float* __restrict__ wproj,
                                               short* __restrict__ xb,
                                               short* __restrict__ wqkvb,
                                               short* __restrict__ wprojb) {
    int i = blockIdx.x * 256 + threadIdx.x;   // grid 8192*256 = 2097152 exactly
    const float* in;
    short* out;
    int idx;
    if (i < 1048576)      { in = x;     out = xb;     idx = i; }
    else if (i < 1835008) { in = wqkv;  out = wqkvb;  idx = i - 1048576; }
    else                  { in = wproj; out = wprojb; idx = i - 1835008; }
    float4 v = ((const float4*)in)[idx];
    short4v o;
    o.x = f2bf(v.x); o.y = f2bf(v.y); o.z = f2bf(v.z); o.w = f2bf(v.w);
    ((short4v*)out)[idx] = o;
}

// ---------------------------------------------------------------------------
// QKV GEMM (bf16 MFMA): C[m,n] = sum_k X[m,k]*W[n,k]
// M=4096, N=3072, K=1024. 128x128 tile, BK=64 as TWO 32-sub-tiles (keeps the
// conflict-free gl_lds16 layout; halves barrier count vs BK=32).
// 1D grid 768 with XCD swizzle: xcd = bid&7 sees only n-tiles {xcd, xcd+8,
// xcd+16} -> W working set 768 KB (fits 4 MB per-XCD L2).
// Q scattered [b,h,l,d] scaled by 0.125*log2e; K [b,h,l,d]; V^T [b,h,d,kpos].
// ---------------------------------------------------------------------------
__global__ __launch_bounds__(256) void gemm_qkv_bf16(const short* __restrict__ A,
                                                     const short* __restrict__ Bm,
                                                     short* __restrict__ Qb,
                                                     short* __restrict__ Kb,
                                                     short* __restrict__ Vb) {
    __shared__ short smem[16384];         // As = smem[0:8192], Bs = smem[8192:16384]
    short* As = smem;                     // [half][128 rows][32 k], half stride 4096
    short* Bs = smem + 8192;
    const int tid = threadIdx.x;
    const int w = tid >> 6, l = tid & 63;
    const int lm = l & 15, q = l >> 4;
    // XCD swizzle: linear -> (m_tile, n_tile) s.t. same-XCD blocks share n-tiles
    const int bid = blockIdx.x;           // 0..767
    const int xcd = bid & 7;
    const int grp = bid >> 3;             // 0..95
    const int n_tile = xcd + 8 * (grp % 3);
    const int m_tile = grp / 3;
    const int m0 = m_tile * 128, n0 = n_tile * 128;
    const int wm = w >> 1, wn = w & 1;

    float4v acc[4][4];
#pragma unroll
    for (int mt = 0; mt < 4; ++mt)
#pragma unroll
        for (int nt = 0; nt < 4; ++nt) acc[mt][nt] = (float4v){0.f, 0.f, 0.f, 0.f};

    for (int k0 = 0; k0 < 1024; k0 += 64) {
        __syncthreads();
#pragma unroll
        for (int h = 0; h < 2; ++h) {
#pragma unroll
            for (int t = 0; t < 2; ++t) {
                int idx8 = w * 128 + t * 64 + l;
                int row = idx8 >> 2, c8 = idx8 & 3;
                gl_lds16(A  + (size_t)(m0 + row) * 1024 + k0 + h * 32 + c8 * 8,
                         (char*)As + h * 8192 + w * 2048 + t * 1024);
                gl_lds16(Bm + (size_t)(n0 + row) * 1024 + k0 + h * 32 + c8 * 8,
                         (char*)Bs + h * 8192 + w * 2048 + t * 1024);
            }
        }
        __syncthreads();
#pragma unroll
        for (int h = 0; h < 2; ++h) {
            short8 af[4], bfr[4];
#pragma unroll
            for (int mt = 0; mt < 4; ++mt)
                af[mt] = *(const short8*)(As + h * 4096 + (wm * 64 + mt * 16 + lm) * 32 + q * 8);
#pragma unroll
            for (int nt = 0; nt < 4; ++nt)
                bfr[nt] = *(const short8*)(Bs + h * 4096 + (wn * 64 + nt * 16 + lm) * 32 + q * 8);
#pragma unroll
            for (int mt = 0; mt < 4; ++mt)
#pragma unroll
                for (int nt = 0; nt < 4; ++nt)
                    acc[mt][nt] = __builtin_amdgcn_mfma_f32_16x16x32_bf16(af[mt], bfr[nt], acc[mt][nt], 0, 0, 0);
        }
    }

    // C layout: col = lane&15, row = quad*4 + reg
    const int which = n0 >> 10;   // uniform per block: 0=Q, 1=K, 2=V
    if (which < 2) {
        short* dst = (which == 0) ? Qb : Kb;
        const float sc = (which == 0) ? QSCALE_ : 1.0f;
        // bounce through LDS in two 64-row halves for coalesced 16B stores
#pragma unroll
        for (int half = 0; half < 2; ++half) {
            __syncthreads();
            if (wm == half) {
#pragma unroll
                for (int mt = 0; mt < 4; ++mt)
#pragma unroll
                    for (int nt = 0; nt < 4; ++nt)
#pragma unroll
                        for (int r = 0; r < 4; ++r)
                            smem[(mt * 16 + q * 4 + r) * 128 + wn * 64 + nt * 16 + lm] =
                                f2bf(acc[mt][nt][r] * sc);
            }
            __syncthreads();
#pragma unroll
            for (int j = 0; j < 4; ++j) {
                const int x = tid + 256 * j;
                const int row = x >> 4, c = x & 15;
                short8 v = *(const short8*)(smem + row * 128 + c * 8);
                const int m = m0 + half * 64 + row;
                const int b = m >> 11, ll = m & 2047;
                const int n = n0 + c * 8;
                const int hh = (n & 1023) >> 6, d = n & 63;
                *(short8*)(dst + (((size_t)b * H_ + hh) * L_ + ll) * HD_ + d) = v;
            }
        }
    } else {
        // V^T: [b][h][d][kpos]; r indexes 4 consecutive kpos -> packed 8B store
#pragma unroll
        for (int mt = 0; mt < 4; ++mt) {
            const int m = m0 + wm * 64 + mt * 16 + q * 4;   // kpos base
            const int b = m >> 11, ll = m & 2047;
#pragma unroll
            for (int nt = 0; nt < 4; ++nt) {
                const int n = n0 + wn * 64 + nt * 16 + lm;
                const int h = (n & 1023) >> 6, d = n & 63;
                short4v pk;
                pk.x = f2bf(acc[mt][nt][0]); pk.y = f2bf(acc[mt][nt][1]);
                pk.z = f2bf(acc[mt][nt][2]); pk.w = f2bf(acc[mt][nt][3]);
                *(short4v*)(Vb + (((size_t)b * H_ + h) * HD_ + d) * L_ + ll) = pk;
            }
        }
    }
}

// ---------------------------------------------------------------------------
// Flash attention v4 + XCD swizzle: 1D grid 512; xcd = bid&7 owns bh in
// [4*xcd, 4*xcd+4) -> per-XCD K/V working set = 4 x 512 KB = 2 MB (fits the
// 4 MB per-XCD L2; was: all 32 bh -> 16 MB thrash, FETCH 69.7 MB).
// Block = 128 q-rows x (b,h); S^T = K Q^T, exp2, P packed via v_perm
// trunc-bf16, O^T = V^T P^T. K/V double-buffered, 1 barrier/iter.
// ---------------------------------------------------------------------------
__global__ __launch_bounds__(256) void attn_mfma(const short* __restrict__ Qb,
                                                 const short* __restrict__ Kb,
                                                 const short* __restrict__ Vtg,
                                                 short* __restrict__ Ob) {
    __shared__ short KV[4 * 4096];   // buf0: K,V ; buf1: K,V (each 64x64 swizzled)
    __shared__ short Pt[128 * 72];   // [qrow][kpos] stride 72; also Q staging area

    const int tid = threadIdx.x;
    const int w = tid >> 6, l = tid & 63;
    const int lm = l & 15, q = l >> 4;
    // XCD swizzle: bid&7 = xcd; bh = xcd*4 + (grp&3); qt = grp>>2. Bijective.
    const int bid = blockIdx.x;           // 0..511
    const int grp = bid >> 3;             // 0..63
    const int bh = (bid & 7) * 4 + (grp & 3);
    const int qt = grp >> 2;              // 0..15

    const short* Qg = Qb  + ((size_t)bh * L_ + qt * 128) * HD_;
    const short* Kg = Kb  + (size_t)bh * L_ * HD_;
    const short* Vg = Vtg + (size_t)bh * HD_ * L_;

    // ---- stage Q once into Pt (swizzled, stride 64); consumed into regs below ----
#pragma unroll
    for (int t = 0; t < 4; ++t) {
        int idx = tid + 256 * t;
        int row = idx >> 3, c = idx & 7;
        short8 v = *(const short8*)(Qg + row * 64 + c * 8);
        *(short8*)(Pt + row * 64 + ((c ^ (row & 7)) * 8)) = v;
    }

    // K/V staging geometry
    const int srow = tid >> 3;            // 0..31
    const int sc   = tid & 7;             // 0..7
    const int koff0 = srow * 64 + ((sc ^ (srow & 7)) * 8);
    const int koff1 = koff0 + 32 * 64;    // (srow+32)&7 == srow&7

    // tile 0 -> buf0 now; tile 1 -> regs
    {
        short8 ka = *(const short8*)(Kg + (size_t)srow * 64 + sc * 8);
        short8 kb = *(const short8*)(Kg + (size_t)(srow + 32) * 64 + sc * 8);
        short8 va = *(const short8*)(Vg + (size_t)srow * L_ + sc * 8);
        short8 vb = *(const short8*)(Vg + (size_t)(srow + 32) * L_ + sc * 8);
        *(short8*)(KV + koff0) = ka;
        *(short8*)(KV + koff1) = kb;
        *(short8*)(KV + 4096 + koff0) = va;
        *(short8*)(KV + 4096 + koff1) = vb;
    }
    short8 kra = *(const short8*)(Kg + (size_t)(64 + srow) * 64 + sc * 8);
    short8 krb = *(const short8*)(Kg + (size_t)(64 + srow + 32) * 64 + sc * 8);
    short8 vra = *(const short8*)(Vg + (size_t)srow * L_ + 64 + sc * 8);
    short8 vrb = *(const short8*)(Vg + (size_t)(srow + 32) * L_ + 64 + sc * 8);

    __syncthreads();   // Q + tile0 staged

    // Q fragments (loop-invariant, own 32 rows) -- read from Pt, then Pt is dead
    short8 qf[2][2];
#pragma unroll
    for (int nq = 0; nq < 2; ++nq)
#pragma unroll
        for (int kh = 0; kh < 2; ++kh) {
            int row = w * 32 + nq * 16 + lm;
            int ch = kh * 4 + q;
            qf[nq][kh] = *(const short8*)(Pt + row * 64 + ((ch ^ (row & 7)) * 8));
        }

    // hoisted frag offsets (iter-invariant)
    int offA0[4], offA1[4], offV[2][4];
#pragma unroll
    for (int nt = 0; nt < 4; ++nt) {
        const int arow = nt * 16 + lm;
        offA0[nt] = arow * 64 + ((q ^ (arow & 7)) * 8);
        offA1[nt] = arow * 64 + (((4 + q) ^ (arow & 7)) * 8);
#pragma unroll
        for (int kh = 0; kh < 2; ++kh)
            offV[kh][nt] = arow * 64 + (((kh * 4 + q) ^ (arow & 7)) * 8);
    }

    float4v o[4][2];
#pragma unroll
    for (int mt = 0; mt < 4; ++mt)
#pragma unroll
        for (int nq = 0; nq < 2; ++nq) o[mt][nq] = (float4v){0.f, 0.f, 0.f, 0.f};
    float lsum[2] = {0.f, 0.f};

    const int prow = w * 32 + lm;

#pragma unroll 2
    for (int t = 0; t < 32; ++t) {
        const int cur = t & 1;
        short* Kl = KV + cur * 8192;
        short* Vt = Kl + 4096;
        short* Kn = KV + (1 - cur) * 8192;
        short* Vn = Kn + 4096;

        __syncthreads();   // prev iter's reads of buf[!cur] done; buf[cur] writes visible

        if (t < 31) {      // stage tile t+1 into the other buffer
            *(short8*)(Kn + koff0) = kra;
            *(short8*)(Kn + koff1) = krb;
            *(short8*)(Vn + koff0) = vra;
            *(short8*)(Vn + koff1) = vrb;
        }
        if (t < 30) {      // prefetch tile t+2 (lands during next compute phase)
            kra = *(const short8*)(Kg + (size_t)((t + 2) * 64 + srow) * 64 + sc * 8);
            krb = *(const short8*)(Kg + (size_t)((t + 2) * 64 + srow + 32) * 64 + sc * 8);
            vra = *(const short8*)(Vg + (size_t)srow * L_ + (t + 2) * 64 + sc * 8);
            vrb = *(const short8*)(Vg + (size_t)(srow + 32) * L_ + (t + 2) * 64 + sc * 8);
        }

        // S^T = K Q^T : A = K rows (kpos), B = Q rows (qrow)
        float4v st[4][2];
#pragma unroll
        for (int nt = 0; nt < 4; ++nt) {
            short8 a0 = *(const short8*)(Kl + offA0[nt]);
            short8 a1 = *(const short8*)(Kl + offA1[nt]);
#pragma unroll
            for (int nq = 0; nq < 2; ++nq) {
                float4v z = (float4v){0.f, 0.f, 0.f, 0.f};
                z = __builtin_amdgcn_mfma_f32_16x16x32_bf16(a0, qf[nq][0], z, 0, 0, 0);
                z = __builtin_amdgcn_mfma_f32_16x16x32_bf16(a1, qf[nq][1], z, 0, 0, 0);
                st[nt][nq] = z;
            }
        }

        // exp2, per-lane row-sum partials, pack P^T -> Pt (v_perm trunc-bf16)
#pragma unroll
        for (int nt = 0; nt < 4; ++nt)
#pragma unroll
            for (int nq = 0; nq < 2; ++nq) {
                const float e0 = EXP2F(st[nt][nq][0]);
                const float e1 = EXP2F(st[nt][nq][1]);
                const float e2 = EXP2F(st[nt][nq][2]);
                const float e3 = EXP2F(st[nt][nq][3]);
                lsum[nq] += (e0 + e1) + (e2 + e3);
                uint2 pk;
                pk.x = pk_bf_trunc(e0, e1);
                pk.y = pk_bf_trunc(e2, e3);
                *(uint2*)(Pt + (prow + nq * 16) * 72 + nt * 16 + q * 4) = pk;
            }

        // O^T += V^T P^T : A = Vt rows (d), B = Pt rows (own wave's qrows)
#pragma unroll
        for (int kh = 0; kh < 2; ++kh) {
            short8 pb[2];
#pragma unroll
            for (int nq = 0; nq < 2; ++nq)
                pb[nq] = *(const short8*)(Pt + (prow + nq * 16) * 72 + kh * 32 + q * 8);
#pragma unroll
            for (int mt = 0; mt < 4; ++mt) {
                short8 va = *(const short8*)(Vt + offV[kh][mt]);
#pragma unroll
                for (int nq = 0; nq < 2; ++nq)
                    o[mt][nq] = __builtin_amdgcn_mfma_f32_16x16x32_bf16(va, pb[nq], o[mt][nq], 0, 0, 0);
            }
        }
    }

    // reduce row-sums across the 4 quads (same lm), normalize, store
    float inv[2];
#pragma unroll
    for (int nq = 0; nq < 2; ++nq) {
        float s = lsum[nq];
        s += __shfl_xor(s, 16);
        s += __shfl_xor(s, 32);
        inv[nq] = 1.f / s;
    }
    short* OgBase = Ob + ((size_t)bh * L_ + qt * 128) * HD_;
#pragma unroll
    for (int nq = 0; nq < 2; ++nq) {
        const int qrow = w * 32 + nq * 16 + lm;
#pragma unroll
        for (int mt = 0; mt < 4; ++mt) {
            short4v pk;
            pk.x = f2bf(o[mt][nq][0] * inv[nq]);
            pk.y = f2bf(o[mt][nq][1] * inv[nq]);
            pk.z = f2bf(o[mt][nq][2] * inv[nq]);
            pk.w = f2bf(o[mt][nq][3] * inv[nq]);
            *(short4v*)(OgBase + (size_t)qrow * 64 + mt * 16 + q * 4) = pk;
        }
    }
}

// ---------------------------------------------------------------------------
// Proj GEMM (bf16 MFMA): out[m,n] = sum_k O[m,k]*Wp[n,k], fp32 out.
// A read from [B,H,L,hd] (k = h*64+d; k0 is 64-aligned -> one head per iter).
// 64x128 tile, BK=64 as two 32-sub-tiles. 1D grid 512 with XCD swizzle:
// n_tile = bid&7 -> each XCD reads ONE 256 KB W strip (L2-resident).
// ---------------------------------------------------------------------------
__global__ __launch_bounds__(256) void gemm_proj_bf16(const short* __restrict__ Ob,
                                                      const short* __restrict__ Wp,
                                                      float* __restrict__ out) {
    __shared__ short As[2 * 2048];   // [half][64 rows][32 k]
    __shared__ short Bs[2 * 4096];   // [half][128 rows][32 k]
    const int tid = threadIdx.x;
    const int w = tid >> 6, l = tid & 63;
    const int lm = l & 15, q = l >> 4;
    const int bid = blockIdx.x;           // 0..511
    const int m0 = (bid >> 3) * 64, n0 = (bid & 7) * 128;
    const int wm = w & 1, wn = w >> 1;
    const int b = m0 >> 11, l0 = m0 & 2047;

    float4v acc[2][4];
#pragma unroll
    for (int mt = 0; mt < 2; ++mt)
#pragma unroll
        for (int nt = 0; nt < 4; ++nt) acc[mt][nt] = (float4v){0.f, 0.f, 0.f, 0.f};

    for (int k0 = 0; k0 < 1024; k0 += 64) {
        const int hh = k0 >> 6;   // head index, uniform per iter
        __syncthreads();
#pragma unroll
        for (int h = 0; h < 2; ++h) {
            {
                int idx8 = w * 64 + l;
                int row = idx8 >> 2, c8 = idx8 & 3;
                gl_lds16(Ob + (((size_t)b * H_ + hh) * L_ + l0 + row) * HD_ + h * 32 + c8 * 8,
                         (char*)As + h * 4096 + w * 1024);
            }
#pragma unroll
            for (int t = 0; t < 2; ++t) {
                int idx8 = w * 128 + t * 64 + l;
                int row = idx8 >> 2, c8 = idx8 & 3;
                gl_lds16(Wp + (size_t)(n0 + row) * 1024 + k0 + h * 32 + c8 * 8,
                         (char*)Bs + h * 8192 + w * 2048 + t * 1024);
            }
        }
        __syncthreads();
#pragma unroll
        for (int h = 0; h < 2; ++h) {
            short8 af[2], bfr[4];
#pragma unroll
            for (int mt = 0; mt < 2; ++mt)
                af[mt] = *(const short8*)(As + h * 2048 + (wm * 32 + mt * 16 + lm) * 32 + q * 8);
#pragma unroll
            for (int nt = 0; nt < 4; ++nt)
                bfr[nt] = *(const short8*)(Bs + h * 4096 + (wn * 64 + nt * 16 + lm) * 32 + q * 8);
#pragma unroll
            for (int mt = 0; mt < 2; ++mt)
#pragma unroll
                for (int nt = 0; nt < 4; ++nt)
                    acc[mt][nt] = __builtin_amdgcn_mfma_f32_16x16x32_bf16(af[mt], bfr[nt], acc[mt][nt], 0, 0, 0);
        }
    }

#pragma unroll
    for (int mt = 0; mt < 2; ++mt)
#pragma unroll
        for (int nt = 0; nt < 4; ++nt)
#pragma unroll
            for (int r = 0; r < 4; ++r) {
                const int m = m0 + wm * 32 + mt * 16 + q * 4 + r;
                const int n = n0 + wn * 64 + nt * 16 + lm;
                out[(size_t)m * 1024 + n] = acc[mt][nt][r];
            }
}

// ---------------------------------------------------------------------------
extern "C" void kernel_launch(void* const* d_in, const int* in_sizes, int n_in,
                              void* d_out, int out_size, void* d_ws, size_t ws_size,
                              hipStream_t stream) {
    (void)in_sizes; (void)n_in; (void)out_size; (void)ws_size;
    const float* x      = (const float*)d_in[0];
    const float* w_qkv  = (const float*)d_in[1];
    const float* w_proj = (const float*)d_in[2];

    char* ws = (char*)d_ws;                       // 48 MiB used
    short* xb     = (short*)(ws);                 // 8 MiB
    short* wqkvb  = (short*)(ws + (8u  << 20));   // 6 MiB
    short* wprojb = (short*)(ws + (14u << 20));   // 2 MiB
    short* Qb     = (short*)(ws + (16u << 20));   // 8 MiB  [b,h,l,d], scaled 0.125*log2e
    short* Kb     = (short*)(ws + (24u << 20));   // 8 MiB  [b,h,l,d]
    short* Vb     = (short*)(ws + (32u << 20));   // 8 MiB  [b,h,d,kpos] (transposed!)
    short* Ob     = (short*)(ws + (40u << 20));   // 8 MiB  attention output [b,h,l,d]

    cvt_all<<<8192, 256, 0, stream>>>(x, w_qkv, w_proj, xb, wqkvb, wprojb);
    gemm_qkv_bf16 <<<768, 256, 0, stream>>>(xb, wqkvb, Qb, Kb, Vb);
    attn_mfma     <<<512, 256, 0, stream>>>(Qb, Kb, Vb, Ob);
    gemm_proj_bf16<<<512, 256, 0, stream>>>(Ob, wprojb, (float*)d_out);
}

// Round 10
// 182.904 us; speedup vs baseline: 1.1402x; 1.0521x over previous
//
#include <hip/hip_runtime.h>
#include <math.h>
#include <stdint.h>

// Problem constants
#define B_ 2
#define L_ 2048
#define D_ 1024
#define H_ 16
#define HD_ 64
// Q scale = 1/8 (softmax scale) * log2(e), folding exp->exp2
#define QSCALE_ 0.1803368801f

typedef __attribute__((ext_vector_type(8))) short short8;   // 8 bf16 = 4 VGPRs (MFMA A/B frag)
typedef __attribute__((ext_vector_type(4))) short short4v;
typedef __attribute__((ext_vector_type(4))) float float4v;  // MFMA C/D frag

#if defined(__has_builtin)
#if __has_builtin(__builtin_amdgcn_exp2f)
#define EXP2F(x) __builtin_amdgcn_exp2f(x)
#endif
#endif
#ifndef EXP2F
#define EXP2F(x) exp2f(x)
#endif

// fp32 -> bf16 round-to-nearest-even (bit pattern as short)
__device__ __forceinline__ short f2bf(float f) {
    union { float f; unsigned u; } x; x.f = f;
    unsigned r = x.u + 0x7fffu + ((x.u >> 16) & 1u);
    return (short)(r >> 16);
}

__device__ __forceinline__ unsigned fbits(float f) {
    union { float f; unsigned u; } x; x.f = f;
    return x.u;
}

// pack trunc-bf16(a) | trunc-bf16(b)<<16 in ONE v_perm_b32
__device__ __forceinline__ unsigned pk_bf_trunc(float a, float b) {
    return __builtin_amdgcn_perm(fbits(b), fbits(a), 0x07060302u);
}

// ---------------------------------------------------------------------------
// Cast ALL inputs fp32->bf16 in one launch.
// x: 1048576 float4 groups; w_qkv: 786432; w_proj: 262144. Total 2097152.
// ---------------------------------------------------------------------------
__global__ __launch_bounds__(256) void cvt_all(const float* __restrict__ x,
                                               const float* __restrict__ wqkv,
                                               const float* __restrict__ wproj,
                                               short* __restrict__ xb,
                                               short* __restrict__ wqkvb,
                                               short* __restrict__ wprojb) {
    int i = blockIdx.x * 256 + threadIdx.x;   // grid 8192*256 = 2097152 exactly
    const float* in;
    short* out;
    int idx;
    if (i < 1048576)      { in = x;     out = xb;     idx = i; }
    else if (i < 1835008) { in = wqkv;  out = wqkvb;  idx = i - 1048576; }
    else                  { in = wproj; out = wprojb; idx = i - 1835008; }
    float4 v = ((const float4*)in)[idx];
    short4v o;
    o.x = f2bf(v.x); o.y = f2bf(v.y); o.z = f2bf(v.z); o.w = f2bf(v.w);
    ((short4v*)out)[idx] = o;
}

// ---------------------------------------------------------------------------
// QKV GEMM v2 (bf16 MFMA, attn-style pipelined staging): C[m,n] = X W^T.
// M=4096, N=3072, K=1024. 128x128 tile, BK=32, 32 k-iters.
// Register-prefetch (distance 2) + LDS double-buffer + ONE barrier/iter:
// the vmcnt wait lands on next iter's ds_write, so global loads stay in
// flight across the barrier (no vmcnt(0) drain like the gl_lds16 version).
// 1D grid 768, XCD swizzle: xcd = bid&7 -> n-tiles {xcd, xcd+8, xcd+16},
// W working set 768 KB (L2-resident). Epilogues unchanged from R7.
// ---------------------------------------------------------------------------
__global__ __launch_bounds__(256) void gemm_qkv_bf16(const short* __restrict__ A,
                                                     const short* __restrict__ Bm,
                                                     short* __restrict__ Qb,
                                                     short* __restrict__ Kb,
                                                     short* __restrict__ Vb) {
    __shared__ short smem[16384];   // As0[0:4096] As1[4096:8192] Bs0[8192:12288] Bs1
    const int tid = threadIdx.x;
    const int w = tid >> 6, l = tid & 63;
    const int lm = l & 15, q = l >> 4;
    const int bid = blockIdx.x;           // 0..767
    const int xcd = bid & 7;
    const int grp = bid >> 3;             // 0..95
    const int n_tile = xcd + 8 * (grp % 3);
    const int m_tile = grp / 3;
    const int m0 = m_tile * 128, n0 = n_tile * 128;
    const int wm = w >> 1, wn = w & 1;

    // staging geometry: chunk j*256+tid -> row = chunk>>2 (0..127), col8 = chunk&3
    const int srow = tid >> 2;            // 0..63 (chunk tid); +64 for chunk tid+256
    const int sc8  = (tid & 3) * 8;       // 0,8,16,24
    const int soff0 = srow * 32 + sc8;
    const int soff1 = soff0 + 64 * 32;
    const short* Ag = A  + (size_t)(m0 + srow) * 1024 + sc8;   // +64 rows via 65536
    const short* Bg = Bm + (size_t)(n0 + srow) * 1024 + sc8;

    float4v acc[4][4];
#pragma unroll
    for (int mt = 0; mt < 4; ++mt)
#pragma unroll
        for (int nt = 0; nt < 4; ++nt) acc[mt][nt] = (float4v){0.f, 0.f, 0.f, 0.f};

    // prologue: tile 0 -> buf0; tile 1 -> regs
    {
        short8 a0 = *(const short8*)(Ag);
        short8 a1 = *(const short8*)(Ag + 64 * 1024);
        short8 b0 = *(const short8*)(Bg);
        short8 b1 = *(const short8*)(Bg + 64 * 1024);
        *(short8*)(smem + soff0) = a0;
        *(short8*)(smem + soff1) = a1;
        *(short8*)(smem + 8192 + soff0) = b0;
        *(short8*)(smem + 8192 + soff1) = b1;
    }
    short8 ar0 = *(const short8*)(Ag + 32);
    short8 ar1 = *(const short8*)(Ag + 64 * 1024 + 32);
    short8 br0 = *(const short8*)(Bg + 32);
    short8 br1 = *(const short8*)(Bg + 64 * 1024 + 32);

    for (int t = 0; t < 32; ++t) {
        const int cur = t & 1;
        short* Asc = smem + cur * 4096;
        short* Asn = smem + (1 - cur) * 4096;
        short* Bsc = smem + 8192 + cur * 4096;
        short* Bsn = smem + 8192 + (1 - cur) * 4096;

        __syncthreads();   // all waves done reading buf[!cur] (iter t-1); buf[cur] visible

        if (t < 31) {      // stage tile t+1 (vmcnt wait attaches here, 1 iter of slack)
            *(short8*)(Asn + soff0) = ar0;
            *(short8*)(Asn + soff1) = ar1;
            *(short8*)(Bsn + soff0) = br0;
            *(short8*)(Bsn + soff1) = br1;
        }
        if (t < 30) {      // prefetch tile t+2
            const int k0 = (t + 2) * 32;
            ar0 = *(const short8*)(Ag + k0);
            ar1 = *(const short8*)(Ag + 64 * 1024 + k0);
            br0 = *(const short8*)(Bg + k0);
            br1 = *(const short8*)(Bg + 64 * 1024 + k0);
        }

        short8 af[4], bfr[4];
#pragma unroll
        for (int mt = 0; mt < 4; ++mt)
            af[mt] = *(const short8*)(Asc + (wm * 64 + mt * 16 + lm) * 32 + q * 8);
#pragma unroll
        for (int nt = 0; nt < 4; ++nt)
            bfr[nt] = *(const short8*)(Bsc + (wn * 64 + nt * 16 + lm) * 32 + q * 8);
#pragma unroll
        for (int mt = 0; mt < 4; ++mt)
#pragma unroll
            for (int nt = 0; nt < 4; ++nt)
                acc[mt][nt] = __builtin_amdgcn_mfma_f32_16x16x32_bf16(af[mt], bfr[nt], acc[mt][nt], 0, 0, 0);
    }

    // C layout: col = lane&15, row = quad*4 + reg
    const int which = n0 >> 10;   // uniform per block: 0=Q, 1=K, 2=V
    if (which < 2) {
        short* dst = (which == 0) ? Qb : Kb;
        const float sc = (which == 0) ? QSCALE_ : 1.0f;
        // bounce through LDS in two 64-row halves for coalesced 16B stores
#pragma unroll
        for (int half = 0; half < 2; ++half) {
            __syncthreads();
            if (wm == half) {
#pragma unroll
                for (int mt = 0; mt < 4; ++mt)
#pragma unroll
                    for (int nt = 0; nt < 4; ++nt)
#pragma unroll
                        for (int r = 0; r < 4; ++r)
                            smem[(mt * 16 + q * 4 + r) * 128 + wn * 64 + nt * 16 + lm] =
                                f2bf(acc[mt][nt][r] * sc);
            }
            __syncthreads();
#pragma unroll
            for (int j = 0; j < 4; ++j) {
                const int x = tid + 256 * j;
                const int row = x >> 4, c = x & 15;
                short8 v = *(const short8*)(smem + row * 128 + c * 8);
                const int m = m0 + half * 64 + row;
                const int b = m >> 11, ll = m & 2047;
                const int n = n0 + c * 8;
                const int hh = (n & 1023) >> 6, d = n & 63;
                *(short8*)(dst + (((size_t)b * H_ + hh) * L_ + ll) * HD_ + d) = v;
            }
        }
    } else {
        // V^T: [b][h][d][kpos]; r indexes 4 consecutive kpos -> packed 8B store
#pragma unroll
        for (int mt = 0; mt < 4; ++mt) {
            const int m = m0 + wm * 64 + mt * 16 + q * 4;   // kpos base
            const int b = m >> 11, ll = m & 2047;
#pragma unroll
            for (int nt = 0; nt < 4; ++nt) {
                const int n = n0 + wn * 64 + nt * 16 + lm;
                const int h = (n & 1023) >> 6, d = n & 63;
                short4v pk;
                pk.x = f2bf(acc[mt][nt][0]); pk.y = f2bf(acc[mt][nt][1]);
                pk.z = f2bf(acc[mt][nt][2]); pk.w = f2bf(acc[mt][nt][3]);
                *(short4v*)(Vb + (((size_t)b * H_ + h) * HD_ + d) * L_ + ll) = pk;
            }
        }
    }
}

// ---------------------------------------------------------------------------
// Flash attention v4 + XCD swizzle (R8, replay-proven): 1D grid 512;
// xcd = bid&7 owns bh in [4*xcd, 4*xcd+4) -> per-XCD K/V working set 2 MB
// (L2-resident; FETCH 12.3 MB). S^T = K Q^T, exp2, P via v_perm trunc-bf16,
// O^T = V^T P^T. K/V double-buffered, 1 barrier/iter.
// ---------------------------------------------------------------------------
__global__ __launch_bounds__(256) void attn_mfma(const short* __restrict__ Qb,
                                                 const short* __restrict__ Kb,
                                                 const short* __restrict__ Vtg,
                                                 short* __restrict__ Ob) {
    __shared__ short KV[4 * 4096];   // buf0: K,V ; buf1: K,V (each 64x64 swizzled)
    __shared__ short Pt[128 * 72];   // [qrow][kpos] stride 72; also Q staging area

    const int tid = threadIdx.x;
    const int w = tid >> 6, l = tid & 63;
    const int lm = l & 15, q = l >> 4;
    const int bid = blockIdx.x;           // 0..511
    const int grp = bid >> 3;             // 0..63
    const int bh = (bid & 7) * 4 + (grp & 3);
    const int qt = grp >> 2;              // 0..15

    const short* Qg = Qb  + ((size_t)bh * L_ + qt * 128) * HD_;
    const short* Kg = Kb  + (size_t)bh * L_ * HD_;
    const short* Vg = Vtg + (size_t)bh * HD_ * L_;

    // ---- stage Q once into Pt (swizzled, stride 64); consumed into regs below ----
#pragma unroll
    for (int t = 0; t < 4; ++t) {
        int idx = tid + 256 * t;
        int row = idx >> 3, c = idx & 7;
        short8 v = *(const short8*)(Qg + row * 64 + c * 8);
        *(short8*)(Pt + row * 64 + ((c ^ (row & 7)) * 8)) = v;
    }

    // K/V staging geometry
    const int srow = tid >> 3;            // 0..31
    const int sc   = tid & 7;             // 0..7
    const int koff0 = srow * 64 + ((sc ^ (srow & 7)) * 8);
    const int koff1 = koff0 + 32 * 64;    // (srow+32)&7 == srow&7

    // tile 0 -> buf0 now; tile 1 -> regs
    {
        short8 ka = *(const short8*)(Kg + (size_t)srow * 64 + sc * 8);
        short8 kb = *(const short8*)(Kg + (size_t)(srow + 32) * 64 + sc * 8);
        short8 va = *(const short8*)(Vg + (size_t)srow * L_ + sc * 8);
        short8 vb = *(const short8*)(Vg + (size_t)(srow + 32) * L_ + sc * 8);
        *(short8*)(KV + koff0) = ka;
        *(short8*)(KV + koff1) = kb;
        *(short8*)(KV + 4096 + koff0) = va;
        *(short8*)(KV + 4096 + koff1) = vb;
    }
    short8 kra = *(const short8*)(Kg + (size_t)(64 + srow) * 64 + sc * 8);
    short8 krb = *(const short8*)(Kg + (size_t)(64 + srow + 32) * 64 + sc * 8);
    short8 vra = *(const short8*)(Vg + (size_t)srow * L_ + 64 + sc * 8);
    short8 vrb = *(const short8*)(Vg + (size_t)(srow + 32) * L_ + 64 + sc * 8);

    __syncthreads();   // Q + tile0 staged

    // Q fragments (loop-invariant, own 32 rows) -- read from Pt, then Pt is dead
    short8 qf[2][2];
#pragma unroll
    for (int nq = 0; nq < 2; ++nq)
#pragma unroll
        for (int kh = 0; kh < 2; ++kh) {
            int row = w * 32 + nq * 16 + lm;
            int ch = kh * 4 + q;
            qf[nq][kh] = *(const short8*)(Pt + row * 64 + ((ch ^ (row & 7)) * 8));
        }

    // hoisted frag offsets (iter-invariant)
    int offA0[4], offA1[4], offV[2][4];
#pragma unroll
    for (int nt = 0; nt < 4; ++nt) {
        const int arow = nt * 16 + lm;
        offA0[nt] = arow * 64 + ((q ^ (arow & 7)) * 8);
        offA1[nt] = arow * 64 + (((4 + q) ^ (arow & 7)) * 8);
#pragma unroll
        for (int kh = 0; kh < 2; ++kh)
            offV[kh][nt] = arow * 64 + (((kh * 4 + q) ^ (arow & 7)) * 8);
    }

    float4v o[4][2];
#pragma unroll
    for (int mt = 0; mt < 4; ++mt)
#pragma unroll
        for (int nq = 0; nq < 2; ++nq) o[mt][nq] = (float4v){0.f, 0.f, 0.f, 0.f};
    float lsum[2] = {0.f, 0.f};

    const int prow = w * 32 + lm;

#pragma unroll 2
    for (int t = 0; t < 32; ++t) {
        const int cur = t & 1;
        short* Kl = KV + cur * 8192;
        short* Vt = Kl + 4096;
        short* Kn = KV + (1 - cur) * 8192;
        short* Vn = Kn + 4096;

        __syncthreads();   // prev iter's reads of buf[!cur] done; buf[cur] writes visible

        if (t < 31) {      // stage tile t+1 into the other buffer
            *(short8*)(Kn + koff0) = kra;
            *(short8*)(Kn + koff1) = krb;
            *(short8*)(Vn + koff0) = vra;
            *(short8*)(Vn + koff1) = vrb;
        }
        if (t < 30) {      // prefetch tile t+2 (lands during next compute phase)
            kra = *(const short8*)(Kg + (size_t)((t + 2) * 64 + srow) * 64 + sc * 8);
            krb = *(const short8*)(Kg + (size_t)((t + 2) * 64 + srow + 32) * 64 + sc * 8);
            vra = *(const short8*)(Vg + (size_t)srow * L_ + (t + 2) * 64 + sc * 8);
            vrb = *(const short8*)(Vg + (size_t)(srow + 32) * L_ + (t + 2) * 64 + sc * 8);
        }

        // S^T = K Q^T : A = K rows (kpos), B = Q rows (qrow)
        float4v st[4][2];
#pragma unroll
        for (int nt = 0; nt < 4; ++nt) {
            short8 a0 = *(const short8*)(Kl + offA0[nt]);
            short8 a1 = *(const short8*)(Kl + offA1[nt]);
#pragma unroll
            for (int nq = 0; nq < 2; ++nq) {
                float4v z = (float4v){0.f, 0.f, 0.f, 0.f};
                z = __builtin_amdgcn_mfma_f32_16x16x32_bf16(a0, qf[nq][0], z, 0, 0, 0);
                z = __builtin_amdgcn_mfma_f32_16x16x32_bf16(a1, qf[nq][1], z, 0, 0, 0);
                st[nt][nq] = z;
            }
        }

        // exp2, per-lane row-sum partials, pack P^T -> Pt (v_perm trunc-bf16)
#pragma unroll
        for (int nt = 0; nt < 4; ++nt)
#pragma unroll
            for (int nq = 0; nq < 2; ++nq) {
                const float e0 = EXP2F(st[nt][nq][0]);
                const float e1 = EXP2F(st[nt][nq][1]);
                const float e2 = EXP2F(st[nt][nq][2]);
                const float e3 = EXP2F(st[nt][nq][3]);
                lsum[nq] += (e0 + e1) + (e2 + e3);
                uint2 pk;
                pk.x = pk_bf_trunc(e0, e1);
                pk.y = pk_bf_trunc(e2, e3);
                *(uint2*)(Pt + (prow + nq * 16) * 72 + nt * 16 + q * 4) = pk;
            }

        // O^T += V^T P^T : A = Vt rows (d), B = Pt rows (own wave's qrows)
#pragma unroll
        for (int kh = 0; kh < 2; ++kh) {
            short8 pb[2];
#pragma unroll
            for (int nq = 0; nq < 2; ++nq)
                pb[nq] = *(const short8*)(Pt + (prow + nq * 16) * 72 + kh * 32 + q * 8);
#pragma unroll
            for (int mt = 0; mt < 4; ++mt) {
                short8 va = *(const short8*)(Vt + offV[kh][mt]);
#pragma unroll
                for (int nq = 0; nq < 2; ++nq)
                    o[mt][nq] = __builtin_amdgcn_mfma_f32_16x16x32_bf16(va, pb[nq], o[mt][nq], 0, 0, 0);
            }
        }
    }

    // reduce row-sums across the 4 quads (same lm), normalize, store
    float inv[2];
#pragma unroll
    for (int nq = 0; nq < 2; ++nq) {
        float s = lsum[nq];
        s += __shfl_xor(s, 16);
        s += __shfl_xor(s, 32);
        inv[nq] = 1.f / s;
    }
    short* OgBase = Ob + ((size_t)bh * L_ + qt * 128) * HD_;
#pragma unroll
    for (int nq = 0; nq < 2; ++nq) {
        const int qrow = w * 32 + nq * 16 + lm;
#pragma unroll
        for (int mt = 0; mt < 4; ++mt) {
            short4v pk;
            pk.x = f2bf(o[mt][nq][0] * inv[nq]);
            pk.y = f2bf(o[mt][nq][1] * inv[nq]);
            pk.z = f2bf(o[mt][nq][2] * inv[nq]);
            pk.w = f2bf(o[mt][nq][3] * inv[nq]);
            *(short4v*)(OgBase + (size_t)qrow * 64 + mt * 16 + q * 4) = pk;
        }
    }
}

// ---------------------------------------------------------------------------
// Proj GEMM v2 (bf16 MFMA, pipelined staging): out[m,n] = sum_k O[m,k]*Wp[n,k].
// A from [B,H,L,hd] (k = h*64+d). 64x128 tile, BK=32, 32 iters, reg-prefetch
// dist 2 + LDS dbuf + 1 barrier/iter. 1D grid 512, XCD swizzle: n_tile =
// bid&7 -> each XCD reads ONE 256 KB W strip (L2-resident). fp32 out.
// ---------------------------------------------------------------------------
__global__ __launch_bounds__(256) void gemm_proj_bf16(const short* __restrict__ Ob,
                                                      const short* __restrict__ Wp,
                                                      float* __restrict__ out) {
    __shared__ short As[2 * 2048];   // 64x32 per buf
    __shared__ short Bs[2 * 4096];   // 128x32 per buf
    const int tid = threadIdx.x;
    const int w = tid >> 6, l = tid & 63;
    const int lm = l & 15, q = l >> 4;
    const int bid = blockIdx.x;           // 0..511
    const int m0 = (bid >> 3) * 64, n0 = (bid & 7) * 128;
    const int wm = w & 1, wn = w >> 1;
    const int b = m0 >> 11, l0 = m0 & 2047;

    // staging geometry
    const int srow = tid >> 2;            // 0..63
    const int sc8  = (tid & 3) * 8;       // 0,8,16,24
    const int aoff = srow * 32 + sc8;     // A: one chunk/thread
    const int boff0 = aoff;               // B: chunks tid and tid+256
    const int boff1 = aoff + 64 * 32;
    const short* Agb = Ob + (((size_t)b * H_) * L_ + l0 + srow) * HD_;  // + hh*L*64 + d
    const short* Bg  = Wp + (size_t)(n0 + srow) * 1024 + sc8;

    float4v acc[2][4];
#pragma unroll
    for (int mt = 0; mt < 2; ++mt)
#pragma unroll
        for (int nt = 0; nt < 4; ++nt) acc[mt][nt] = (float4v){0.f, 0.f, 0.f, 0.f};

    // k-tile t covers k = t*32: hh = t>>1, d = (t&1)*32 + sc8
    // prologue: tile 0 -> buf0; tile 1 -> regs
    {
        short8 a0 = *(const short8*)(Agb + sc8);                       // t=0: hh=0, d=sc8
        short8 b0 = *(const short8*)(Bg);
        short8 b1 = *(const short8*)(Bg + 64 * 1024);
        *(short8*)(As + aoff) = a0;
        *(short8*)(Bs + boff0) = b0;
        *(short8*)(Bs + boff1) = b1;
    }
    short8 arx = *(const short8*)(Agb + 32 + sc8);                     // t=1: hh=0, d=32+sc8
    short8 brx0 = *(const short8*)(Bg + 32);
    short8 brx1 = *(const short8*)(Bg + 64 * 1024 + 32);

    for (int t = 0; t < 32; ++t) {
        const int cur = t & 1;
        short* Asc = As + cur * 2048;
        short* Asn = As + (1 - cur) * 2048;
        short* Bsc = Bs + cur * 4096;
        short* Bsn = Bs + (1 - cur) * 4096;

        __syncthreads();

        if (t < 31) {
            *(short8*)(Asn + aoff) = arx;
            *(short8*)(Bsn + boff0) = brx0;
            *(short8*)(Bsn + boff1) = brx1;
        }
        if (t < 30) {
            const int tn = t + 2;
            const int hh = tn >> 1, d = (tn & 1) * 32 + sc8;
            arx  = *(const short8*)(Agb + (size_t)hh * L_ * HD_ + d);
            brx0 = *(const short8*)(Bg + tn * 32);
            brx1 = *(const short8*)(Bg + 64 * 1024 + tn * 32);
        }

        short8 af[2], bfr[4];
#pragma unroll
        for (int mt = 0; mt < 2; ++mt)
            af[mt] = *(const short8*)(Asc + (wm * 32 + mt * 16 + lm) * 32 + q * 8);
#pragma unroll
        for (int nt = 0; nt < 4; ++nt)
            bfr[nt] = *(const short8*)(Bsc + (wn * 64 + nt * 16 + lm) * 32 + q * 8);
#pragma unroll
        for (int mt = 0; mt < 2; ++mt)
#pragma unroll
            for (int nt = 0; nt < 4; ++nt)
                acc[mt][nt] = __builtin_amdgcn_mfma_f32_16x16x32_bf16(af[mt], bfr[nt], acc[mt][nt], 0, 0, 0);
    }

#pragma unroll
    for (int mt = 0; mt < 2; ++mt)
#pragma unroll
        for (int nt = 0; nt < 4; ++nt)
#pragma unroll
            for (int r = 0; r < 4; ++r) {
                const int m = m0 + wm * 32 + mt * 16 + q * 4 + r;
                const int n = n0 + wn * 64 + nt * 16 + lm;
                out[(size_t)m * 1024 + n] = acc[mt][nt][r];
            }
}

// ---------------------------------------------------------------------------
extern "C" void kernel_launch(void* const* d_in, const int* in_sizes, int n_in,
                              void* d_out, int out_size, void* d_ws, size_t ws_size,
                              hipStream_t stream) {
    (void)in_sizes; (void)n_in; (void)out_size; (void)ws_size;
    const float* x      = (const float*)d_in[0];
    const float* w_qkv  = (const float*)d_in[1];
    const float* w_proj = (const float*)d_in[2];

    char* ws = (char*)d_ws;                       // 48 MiB used
    short* xb     = (short*)(ws);                 // 8 MiB
    short* wqkvb  = (short*)(ws + (8u  << 20));   // 6 MiB
    short* wprojb = (short*)(ws + (14u << 20));   // 2 MiB
    short* Qb     = (short*)(ws + (16u << 20));   // 8 MiB  [b,h,l,d], scaled 0.125*log2e
    short* Kb     = (short*)(ws + (24u << 20));   // 8 MiB  [b,h,l,d]
    short* Vb     = (short*)(ws + (32u << 20));   // 8 MiB  [b,h,d,kpos] (transposed!)
    short* Ob     = (short*)(ws + (40u << 20));   // 8 MiB  attention output [b,h,l,d]

    cvt_all<<<8192, 256, 0, stream>>>(x, w_qkv, w_proj, xb, wqkvb, wprojb);
    gemm_qkv_bf16 <<<768, 256, 0, stream>>>(xb, wqkvb, Qb, Kb, Vb);
    attn_mfma     <<<512, 256, 0, stream>>>(Qb, Kb, Vb, Ob);
    gemm_proj_bf16<<<512, 256, 0, stream>>>(Ob, wprojb, (float*)d_out);
}

// Round 11
// 172.437 us; speedup vs baseline: 1.2094x; 1.0607x over previous
//
#include <hip/hip_runtime.h>
#include <math.h>
#include <stdint.h>

// Problem constants
#define B_ 2
#define L_ 2048
#define D_ 1024
#define H_ 16
#define HD_ 64
// Q scale = 1/8 (softmax scale) * log2(e), folding exp->exp2
#define QSCALE_ 0.1803368801f

typedef __attribute__((ext_vector_type(8))) short short8;   // 8 bf16 = 4 VGPRs (MFMA A/B frag)
typedef __attribute__((ext_vector_type(4))) short short4v;
typedef __attribute__((ext_vector_type(4))) float float4v;  // MFMA C/D frag

#if defined(__has_builtin)
#if __has_builtin(__builtin_amdgcn_exp2f)
#define EXP2F(x) __builtin_amdgcn_exp2f(x)
#endif
#endif
#ifndef EXP2F
#define EXP2F(x) exp2f(x)
#endif

// fp32 -> bf16 round-to-nearest-even (bit pattern as short)
__device__ __forceinline__ short f2bf(float f) {
    union { float f; unsigned u; } x; x.f = f;
    unsigned r = x.u + 0x7fffu + ((x.u >> 16) & 1u);
    return (short)(r >> 16);
}

__device__ __forceinline__ unsigned fbits(float f) {
    union { float f; unsigned u; } x; x.f = f;
    return x.u;
}

// pack trunc-bf16(a) | trunc-bf16(b)<<16 in ONE v_perm_b32
__device__ __forceinline__ unsigned pk_bf_trunc(float a, float b) {
    return __builtin_amdgcn_perm(fbits(b), fbits(a), 0x07060302u);
}

// ---------------------------------------------------------------------------
// Cast ALL inputs fp32->bf16 in one launch.
// ---------------------------------------------------------------------------
__global__ __launch_bounds__(256) void cvt_all(const float* __restrict__ x,
                                               const float* __restrict__ wqkv,
                                               const float* __restrict__ wproj,
                                               short* __restrict__ xb,
                                               short* __restrict__ wqkvb,
                                               short* __restrict__ wprojb) {
    int i = blockIdx.x * 256 + threadIdx.x;   // grid 8192*256 = 2097152 exactly
    const float* in;
    short* out;
    int idx;
    if (i < 1048576)      { in = x;     out = xb;     idx = i; }
    else if (i < 1835008) { in = wqkv;  out = wqkvb;  idx = i - 1048576; }
    else                  { in = wproj; out = wprojb; idx = i - 1835008; }
    float4 v = ((const float4*)in)[idx];
    short4v o;
    o.x = f2bf(v.x); o.y = f2bf(v.y); o.z = f2bf(v.z); o.w = f2bf(v.w);
    ((short4v*)out)[idx] = o;
}

// ---------------------------------------------------------------------------
// QKV GEMM v2 (pipelined staging, R9): C[m,n] = X W^T. 128x128, BK=32,
// reg-prefetch dist 2 + LDS dbuf + 1 barrier/iter. XCD swizzle (W L2-resident).
// Q [b,h,l,d] scaled; K [b,h,l,d]; V^T [b,h,d,slot] with PI-PERMUTED kpos:
// within each 64-token tile, slot = bits(kpos: n1 n0 q1 q0 r1 r0 -> n1 q1 q0 n0 r1 r0)
// so attention's P stays in registers (C-layout == B-operand layout).
// ---------------------------------------------------------------------------
__global__ __launch_bounds__(256) void gemm_qkv_bf16(const short* __restrict__ A,
                                                     const short* __restrict__ Bm,
                                                     short* __restrict__ Qb,
                                                     short* __restrict__ Kb,
                                                     short* __restrict__ Vb) {
    __shared__ short smem[16384];   // As0[0:4096] As1[4096:8192] Bs0[8192:12288] Bs1
    const int tid = threadIdx.x;
    const int w = tid >> 6, l = tid & 63;
    const int lm = l & 15, q = l >> 4;
    const int bid = blockIdx.x;           // 0..767
    const int xcd = bid & 7;
    const int grp = bid >> 3;             // 0..95
    const int n_tile = xcd + 8 * (grp % 3);
    const int m_tile = grp / 3;
    const int m0 = m_tile * 128, n0 = n_tile * 128;
    const int wm = w >> 1, wn = w & 1;

    const int srow = tid >> 2;            // 0..63
    const int sc8  = (tid & 3) * 8;       // 0,8,16,24
    const int soff0 = srow * 32 + sc8;
    const int soff1 = soff0 + 64 * 32;
    const short* Ag = A  + (size_t)(m0 + srow) * 1024 + sc8;
    const short* Bg = Bm + (size_t)(n0 + srow) * 1024 + sc8;

    float4v acc[4][4];
#pragma unroll
    for (int mt = 0; mt < 4; ++mt)
#pragma unroll
        for (int nt = 0; nt < 4; ++nt) acc[mt][nt] = (float4v){0.f, 0.f, 0.f, 0.f};

    {
        short8 a0 = *(const short8*)(Ag);
        short8 a1 = *(const short8*)(Ag + 64 * 1024);
        short8 b0 = *(const short8*)(Bg);
        short8 b1 = *(const short8*)(Bg + 64 * 1024);
        *(short8*)(smem + soff0) = a0;
        *(short8*)(smem + soff1) = a1;
        *(short8*)(smem + 8192 + soff0) = b0;
        *(short8*)(smem + 8192 + soff1) = b1;
    }
    short8 ar0 = *(const short8*)(Ag + 32);
    short8 ar1 = *(const short8*)(Ag + 64 * 1024 + 32);
    short8 br0 = *(const short8*)(Bg + 32);
    short8 br1 = *(const short8*)(Bg + 64 * 1024 + 32);

    for (int t = 0; t < 32; ++t) {
        const int cur = t & 1;
        short* Asc = smem + cur * 4096;
        short* Asn = smem + (1 - cur) * 4096;
        short* Bsc = smem + 8192 + cur * 4096;
        short* Bsn = smem + 8192 + (1 - cur) * 4096;

        __syncthreads();

        if (t < 31) {
            *(short8*)(Asn + soff0) = ar0;
            *(short8*)(Asn + soff1) = ar1;
            *(short8*)(Bsn + soff0) = br0;
            *(short8*)(Bsn + soff1) = br1;
        }
        if (t < 30) {
            const int k0 = (t + 2) * 32;
            ar0 = *(const short8*)(Ag + k0);
            ar1 = *(const short8*)(Ag + 64 * 1024 + k0);
            br0 = *(const short8*)(Bg + k0);
            br1 = *(const short8*)(Bg + 64 * 1024 + k0);
        }

        short8 af[4], bfr[4];
#pragma unroll
        for (int mt = 0; mt < 4; ++mt)
            af[mt] = *(const short8*)(Asc + (wm * 64 + mt * 16 + lm) * 32 + q * 8);
#pragma unroll
        for (int nt = 0; nt < 4; ++nt)
            bfr[nt] = *(const short8*)(Bsc + (wn * 64 + nt * 16 + lm) * 32 + q * 8);
#pragma unroll
        for (int mt = 0; mt < 4; ++mt)
#pragma unroll
            for (int nt = 0; nt < 4; ++nt)
                acc[mt][nt] = __builtin_amdgcn_mfma_f32_16x16x32_bf16(af[mt], bfr[nt], acc[mt][nt], 0, 0, 0);
    }

    // C layout: col = lane&15, row = quad*4 + reg
    const int which = n0 >> 10;   // uniform per block: 0=Q, 1=K, 2=V
    if (which < 2) {
        short* dst = (which == 0) ? Qb : Kb;
        const float sc = (which == 0) ? QSCALE_ : 1.0f;
#pragma unroll
        for (int half = 0; half < 2; ++half) {
            __syncthreads();
            if (wm == half) {
#pragma unroll
                for (int mt = 0; mt < 4; ++mt)
#pragma unroll
                    for (int nt = 0; nt < 4; ++nt)
#pragma unroll
                        for (int r = 0; r < 4; ++r)
                            smem[(mt * 16 + q * 4 + r) * 128 + wn * 64 + nt * 16 + lm] =
                                f2bf(acc[mt][nt][r] * sc);
            }
            __syncthreads();
#pragma unroll
            for (int j = 0; j < 4; ++j) {
                const int x = tid + 256 * j;
                const int row = x >> 4, c = x & 15;
                short8 v = *(const short8*)(smem + row * 128 + c * 8);
                const int m = m0 + half * 64 + row;
                const int b = m >> 11, ll = m & 2047;
                const int n = n0 + c * 8;
                const int hh = (n & 1023) >> 6, d = n & 63;
                *(short8*)(dst + (((size_t)b * H_ + hh) * L_ + ll) * HD_ + d) = v;
            }
        }
    } else {
        // V^T pi-permuted: slot within 64-tile = (mt>>1)*32 + q*8 + (mt&1)*4 + r.
        // r stays in low bits -> still one packed 8B store.
        const int mbase = m0 + wm * 64;              // 64-aligned token base
        const int b = mbase >> 11;
        const int llb = (mbase & 2047);
#pragma unroll
        for (int mt = 0; mt < 4; ++mt) {
            const int ll = llb + (mt >> 1) * 32 + q * 8 + (mt & 1) * 4;
#pragma unroll
            for (int nt = 0; nt < 4; ++nt) {
                const int n = n0 + wn * 64 + nt * 16 + lm;
                const int h = (n & 1023) >> 6, d = n & 63;
                short4v pk;
                pk.x = f2bf(acc[mt][nt][0]); pk.y = f2bf(acc[mt][nt][1]);
                pk.z = f2bf(acc[mt][nt][2]); pk.w = f2bf(acc[mt][nt][3]);
                *(short4v*)(Vb + (((size_t)b * H_ + h) * HD_ + d) * L_ + ll) = pk;
            }
        }
    }
}

// ---------------------------------------------------------------------------
// Flash attention v6: pi-permuted V -> P NEVER touches LDS (C-layout of S^T
// == B-operand layout under the kpos permutation baked into V^T storage).
// LDS/iter: 16 KB staging + 32 KB K-frags + 32 KB V-frags (was 112 KB).
// XCD swizzle (bh L2-locality). K/V dbuf, 1 barrier/iter. LDS 32 KB
// (Q stages through buf1, dead until t=0's barrier).
// ---------------------------------------------------------------------------
__global__ __launch_bounds__(256) void attn_mfma(const short* __restrict__ Qb,
                                                 const short* __restrict__ Kb,
                                                 const short* __restrict__ Vtg,
                                                 short* __restrict__ Ob) {
    __shared__ short KV[4 * 4096];   // buf0: K,V (0..8191); buf1: K,V (8192..16383)

    const int tid = threadIdx.x;
    const int w = tid >> 6, l = tid & 63;
    const int lm = l & 15, q = l >> 4;
    const int bid = blockIdx.x;           // 0..511
    const int grp = bid >> 3;             // 0..63
    const int bh = (bid & 7) * 4 + (grp & 3);
    const int qt = grp >> 2;              // 0..15

    const short* Qg = Qb  + ((size_t)bh * L_ + qt * 128) * HD_;
    const short* Kg = Kb  + (size_t)bh * L_ * HD_;
    const short* Vg = Vtg + (size_t)bh * HD_ * L_;

    // ---- stage Q into buf1 region (dead until t=0 writes it, after a barrier) ----
    short* Qs = KV + 8192;
#pragma unroll
    for (int t = 0; t < 4; ++t) {
        int idx = tid + 256 * t;
        int row = idx >> 3, c = idx & 7;
        short8 v = *(const short8*)(Qg + row * 64 + c * 8);
        *(short8*)(Qs + row * 64 + ((c ^ (row & 7)) * 8)) = v;
    }

    // K/V staging geometry
    const int srow = tid >> 3;            // 0..31
    const int sc   = tid & 7;             // 0..7
    const int koff0 = srow * 64 + ((sc ^ (srow & 7)) * 8);
    const int koff1 = koff0 + 32 * 64;    // (srow+32)&7 == srow&7

    // tile 0 -> buf0 now; tile 1 -> regs
    {
        short8 ka = *(const short8*)(Kg + (size_t)srow * 64 + sc * 8);
        short8 kb = *(const short8*)(Kg + (size_t)(srow + 32) * 64 + sc * 8);
        short8 va = *(const short8*)(Vg + (size_t)srow * L_ + sc * 8);
        short8 vb = *(const short8*)(Vg + (size_t)(srow + 32) * L_ + sc * 8);
        *(short8*)(KV + koff0) = ka;
        *(short8*)(KV + koff1) = kb;
        *(short8*)(KV + 4096 + koff0) = va;
        *(short8*)(KV + 4096 + koff1) = vb;
    }
    short8 kra = *(const short8*)(Kg + (size_t)(64 + srow) * 64 + sc * 8);
    short8 krb = *(const short8*)(Kg + (size_t)(64 + srow + 32) * 64 + sc * 8);
    short8 vra = *(const short8*)(Vg + (size_t)srow * L_ + 64 + sc * 8);
    short8 vrb = *(const short8*)(Vg + (size_t)(srow + 32) * L_ + 64 + sc * 8);

    __syncthreads();   // Q + tile0 staged

    // Q fragments (loop-invariant, own 32 rows); after this Qs (buf1) is dead
    short8 qf[2][2];
#pragma unroll
    for (int nq = 0; nq < 2; ++nq)
#pragma unroll
        for (int kh = 0; kh < 2; ++kh) {
            int row = w * 32 + nq * 16 + lm;
            int ch = kh * 4 + q;
            qf[nq][kh] = *(const short8*)(Qs + row * 64 + ((ch ^ (row & 7)) * 8));
        }

    // hoisted frag offsets (iter-invariant)
    int offA0[4], offA1[4], offV[2][4];
#pragma unroll
    for (int nt = 0; nt < 4; ++nt) {
        const int arow = nt * 16 + lm;
        offA0[nt] = arow * 64 + ((q ^ (arow & 7)) * 8);
        offA1[nt] = arow * 64 + (((4 + q) ^ (arow & 7)) * 8);
#pragma unroll
        for (int kh = 0; kh < 2; ++kh)
            offV[kh][nt] = arow * 64 + (((kh * 4 + q) ^ (arow & 7)) * 8);
    }

    float4v o[4][2];
#pragma unroll
    for (int mt = 0; mt < 4; ++mt)
#pragma unroll
        for (int nq = 0; nq < 2; ++nq) o[mt][nq] = (float4v){0.f, 0.f, 0.f, 0.f};
    float lsum[2] = {0.f, 0.f};

#pragma unroll 2
    for (int t = 0; t < 32; ++t) {
        const int cur = t & 1;
        short* Kl = KV + cur * 8192;
        short* Vt = Kl + 4096;
        short* Kn = KV + (1 - cur) * 8192;
        short* Vn = Kn + 4096;

        __syncthreads();   // prev iter's reads of buf[!cur] done; buf[cur] writes visible

        if (t < 31) {      // stage tile t+1 into the other buffer
            *(short8*)(Kn + koff0) = kra;
            *(short8*)(Kn + koff1) = krb;
            *(short8*)(Vn + koff0) = vra;
            *(short8*)(Vn + koff1) = vrb;
        }
        if (t < 30) {      // prefetch tile t+2
            kra = *(const short8*)(Kg + (size_t)((t + 2) * 64 + srow) * 64 + sc * 8);
            krb = *(const short8*)(Kg + (size_t)((t + 2) * 64 + srow + 32) * 64 + sc * 8);
            vra = *(const short8*)(Vg + (size_t)srow * L_ + (t + 2) * 64 + sc * 8);
            vrb = *(const short8*)(Vg + (size_t)(srow + 32) * L_ + (t + 2) * 64 + sc * 8);
        }

        // S^T = K Q^T : A = K rows (kpos), B = Q rows (qrow)
        float4v st[4][2];
#pragma unroll
        for (int nt = 0; nt < 4; ++nt) {
            short8 a0 = *(const short8*)(Kl + offA0[nt]);
            short8 a1 = *(const short8*)(Kl + offA1[nt]);
#pragma unroll
            for (int nq = 0; nq < 2; ++nq) {
                float4v z = (float4v){0.f, 0.f, 0.f, 0.f};
                z = __builtin_amdgcn_mfma_f32_16x16x32_bf16(a0, qf[nq][0], z, 0, 0, 0);
                z = __builtin_amdgcn_mfma_f32_16x16x32_bf16(a1, qf[nq][1], z, 0, 0, 0);
                st[nt][nq] = z;
            }
        }

        // exp2 + build P B-frags IN REGISTERS (pi-permutation: value (nt,r)
        // -> B slot kh=nt>>1, j=(nt&1)*4+r). Same truncation as before.
        short8 pb[2][2];
#pragma unroll
        for (int nq = 0; nq < 2; ++nq) {
            float e[4][4];
#pragma unroll
            for (int nt = 0; nt < 4; ++nt) {
                e[nt][0] = EXP2F(st[nt][nq][0]);
                e[nt][1] = EXP2F(st[nt][nq][1]);
                e[nt][2] = EXP2F(st[nt][nq][2]);
                e[nt][3] = EXP2F(st[nt][nq][3]);
                lsum[nq] += (e[nt][0] + e[nt][1]) + (e[nt][2] + e[nt][3]);
            }
            union { short8 s8; unsigned u[4]; } p0, p1;
            p0.u[0] = pk_bf_trunc(e[0][0], e[0][1]);
            p0.u[1] = pk_bf_trunc(e[0][2], e[0][3]);
            p0.u[2] = pk_bf_trunc(e[1][0], e[1][1]);
            p0.u[3] = pk_bf_trunc(e[1][2], e[1][3]);
            p1.u[0] = pk_bf_trunc(e[2][0], e[2][1]);
            p1.u[1] = pk_bf_trunc(e[2][2], e[2][3]);
            p1.u[2] = pk_bf_trunc(e[3][0], e[3][1]);
            p1.u[3] = pk_bf_trunc(e[3][2], e[3][3]);
            pb[0][nq] = p0.s8;
            pb[1][nq] = p1.s8;
        }

        // O^T += V^T P^T : A = Vt rows (d) [pi-permuted slots], B = pb regs
#pragma unroll
        for (int kh = 0; kh < 2; ++kh)
#pragma unroll
            for (int mt = 0; mt < 4; ++mt) {
                short8 va = *(const short8*)(Vt + offV[kh][mt]);
#pragma unroll
                for (int nq = 0; nq < 2; ++nq)
                    o[mt][nq] = __builtin_amdgcn_mfma_f32_16x16x32_bf16(va, pb[kh][nq], o[mt][nq], 0, 0, 0);
            }
    }

    // reduce row-sums across the 4 quads (same lm), normalize, store
    float inv[2];
#pragma unroll
    for (int nq = 0; nq < 2; ++nq) {
        float s = lsum[nq];
        s += __shfl_xor(s, 16);
        s += __shfl_xor(s, 32);
        inv[nq] = 1.f / s;
    }
    short* OgBase = Ob + ((size_t)bh * L_ + qt * 128) * HD_;
#pragma unroll
    for (int nq = 0; nq < 2; ++nq) {
        const int qrow = w * 32 + nq * 16 + lm;
#pragma unroll
        for (int mt = 0; mt < 4; ++mt) {
            short4v pk;
            pk.x = f2bf(o[mt][nq][0] * inv[nq]);
            pk.y = f2bf(o[mt][nq][1] * inv[nq]);
            pk.z = f2bf(o[mt][nq][2] * inv[nq]);
            pk.w = f2bf(o[mt][nq][3] * inv[nq]);
            *(short4v*)(OgBase + (size_t)qrow * 64 + mt * 16 + q * 4) = pk;
        }
    }
}

// ---------------------------------------------------------------------------
// Proj GEMM v2 (pipelined staging, R9): out = O Wp^T, fp32 out. 64x128, BK=32,
// reg-prefetch dist 2 + LDS dbuf + 1 barrier/iter. XCD swizzle (W L2-resident).
// ---------------------------------------------------------------------------
__global__ __launch_bounds__(256) void gemm_proj_bf16(const short* __restrict__ Ob,
                                                      const short* __restrict__ Wp,
                                                      float* __restrict__ out) {
    __shared__ short As[2 * 2048];   // 64x32 per buf
    __shared__ short Bs[2 * 4096];   // 128x32 per buf
    const int tid = threadIdx.x;
    const int w = tid >> 6, l = tid & 63;
    const int lm = l & 15, q = l >> 4;
    const int bid = blockIdx.x;           // 0..511
    const int m0 = (bid >> 3) * 64, n0 = (bid & 7) * 128;
    const int wm = w & 1, wn = w >> 1;
    const int b = m0 >> 11, l0 = m0 & 2047;

    const int srow = tid >> 2;            // 0..63
    const int sc8  = (tid & 3) * 8;       // 0,8,16,24
    const int aoff = srow * 32 + sc8;
    const int boff0 = aoff;
    const int boff1 = aoff + 64 * 32;
    const short* Agb = Ob + (((size_t)b * H_) * L_ + l0 + srow) * HD_;
    const short* Bg  = Wp + (size_t)(n0 + srow) * 1024 + sc8;

    float4v acc[2][4];
#pragma unroll
    for (int mt = 0; mt < 2; ++mt)
#pragma unroll
        for (int nt = 0; nt < 4; ++nt) acc[mt][nt] = (float4v){0.f, 0.f, 0.f, 0.f};

    {
        short8 a0 = *(const short8*)(Agb + sc8);
        short8 b0 = *(const short8*)(Bg);
        short8 b1 = *(const short8*)(Bg + 64 * 1024);
        *(short8*)(As + aoff) = a0;
        *(short8*)(Bs + boff0) = b0;
        *(short8*)(Bs + boff1) = b1;
    }
    short8 arx = *(const short8*)(Agb + 32 + sc8);
    short8 brx0 = *(const short8*)(Bg + 32);
    short8 brx1 = *(const short8*)(Bg + 64 * 1024 + 32);

    for (int t = 0; t < 32; ++t) {
        const int cur = t & 1;
        short* Asc = As + cur * 2048;
        short* Asn = As + (1 - cur) * 2048;
        short* Bsc = Bs + cur * 4096;
        short* Bsn = Bs + (1 - cur) * 4096;

        __syncthreads();

        if (t < 31) {
            *(short8*)(Asn + aoff) = arx;
            *(short8*)(Bsn + boff0) = brx0;
            *(short8*)(Bsn + boff1) = brx1;
        }
        if (t < 30) {
            const int tn = t + 2;
            const int hh = tn >> 1, d = (tn & 1) * 32 + sc8;
            arx  = *(const short8*)(Agb + (size_t)hh * L_ * HD_ + d);
            brx0 = *(const short8*)(Bg + tn * 32);
            brx1 = *(const short8*)(Bg + 64 * 1024 + tn * 32);
        }

        short8 af[2], bfr[4];
#pragma unroll
        for (int mt = 0; mt < 2; ++mt)
            af[mt] = *(const short8*)(Asc + (wm * 32 + mt * 16 + lm) * 32 + q * 8);
#pragma unroll
        for (int nt = 0; nt < 4; ++nt)
            bfr[nt] = *(const short8*)(Bsc + (wn * 64 + nt * 16 + lm) * 32 + q * 8);
#pragma unroll
        for (int mt = 0; mt < 2; ++mt)
#pragma unroll
            for (int nt = 0; nt < 4; ++nt)
                acc[mt][nt] = __builtin_amdgcn_mfma_f32_16x16x32_bf16(af[mt], bfr[nt], acc[mt][nt], 0, 0, 0);
    }

#pragma unroll
    for (int mt = 0; mt < 2; ++mt)
#pragma unroll
        for (int nt = 0; nt < 4; ++nt)
#pragma unroll
            for (int r = 0; r < 4; ++r) {
                const int m = m0 + wm * 32 + mt * 16 + q * 4 + r;
                const int n = n0 + wn * 64 + nt * 16 + lm;
                out[(size_t)m * 1024 + n] = acc[mt][nt][r];
            }
}

// ---------------------------------------------------------------------------
extern "C" void kernel_launch(void* const* d_in, const int* in_sizes, int n_in,
                              void* d_out, int out_size, void* d_ws, size_t ws_size,
                              hipStream_t stream) {
    (void)in_sizes; (void)n_in; (void)out_size; (void)ws_size;
    const float* x      = (const float*)d_in[0];
    const float* w_qkv  = (const float*)d_in[1];
    const float* w_proj = (const float*)d_in[2];

    char* ws = (char*)d_ws;                       // 48 MiB used
    short* xb     = (short*)(ws);                 // 8 MiB
    short* wqkvb  = (short*)(ws + (8u  << 20));   // 6 MiB
    short* wprojb = (short*)(ws + (14u << 20));   // 2 MiB
    short* Qb     = (short*)(ws + (16u << 20));   // 8 MiB  [b,h,l,d], scaled 0.125*log2e
    short* Kb     = (short*)(ws + (24u << 20));   // 8 MiB  [b,h,l,d]
    short* Vb     = (short*)(ws + (32u << 20));   // 8 MiB  [b,h,d,slot] pi-permuted V^T
    short* Ob     = (short*)(ws + (40u << 20));   // 8 MiB  attention output [b,h,l,d]

    cvt_all<<<8192, 256, 0, stream>>>(x, w_qkv, w_proj, xb, wqkvb, wprojb);
    gemm_qkv_bf16 <<<768, 256, 0, stream>>>(xb, wqkvb, Qb, Kb, Vb);
    attn_mfma     <<<512, 256, 0, stream>>>(Qb, Kb, Vb, Ob);
    gemm_proj_bf16<<<512, 256, 0, stream>>>(Ob, wprojb, (float*)d_out);
}